// Round 2
// baseline (46629.565 us; speedup 1.0000x reference)
//
#include <hip/hip_runtime.h>
#include <hip/hip_cooperative_groups.h>

namespace cg = cooperative_groups;

#define Tn  512
#define Bn  128
#define INn 64
#define Hn  1024

typedef __attribute__((ext_vector_type(8))) short bf16x8;
typedef __attribute__((ext_vector_type(4))) float f32x4;
typedef unsigned short u16;

__device__ __forceinline__ u16 f2bf(float f) {
  unsigned u = __float_as_uint(f);
  unsigned r = (u + 0x7fffu + ((u >> 16) & 1u)) >> 16;
  return (u16)r;
}
__device__ __forceinline__ float bf2f(u16 h) {
  return __uint_as_float(((unsigned)h) << 16);
}
__device__ __forceinline__ float sigmoidf_(float x) {
  return 1.0f / (1.0f + __expf(-x));
}
__device__ __forceinline__ float tanhf_(float x) {
  float e = __expf(-2.0f * fabsf(x));
  float t = (1.0f - e) / (1.0f + e);
  return copysignf(t, x);
}
__device__ __forceinline__ f32x4 mfma16(bf16x8 a, bf16x8 b, f32x4 c) {
  return __builtin_amdgcn_mfma_f32_16x16x32_bf16(a, b, c, 0, 0, 0);
}

// Repack fp32 weight matrix (R rows x K cols, row = output col of the GEMM)
// into MFMA B-fragment order: d[((ct*(K/32)+kc)*64 + lane)*8 + j]
//   = bf16( s[(ct*16 + (lane&15))*K + kc*32 + (lane>>4)*8 + j] )
// so a wave's B-fragment load is 64 lanes x 16B fully contiguous (1KB).
__global__ void pack_w(const float* __restrict__ s, u16* __restrict__ d, int R, int K) {
  int tid = blockIdx.x * blockDim.x + threadIdx.x;
  int total = (R * K) >> 3;
  if (tid >= total) return;
  int l = tid & 63;
  int ckc = tid >> 6;
  int nkc = K >> 5;
  int ct = ckc / nkc;
  int kc = ckc - ct * nkc;
  int row = ct * 16 + (l & 15);
  int k0 = kc * 32 + (l >> 4) * 8;
  const float* sp = s + (size_t)row * K + k0;
  float4 a = *(const float4*)sp;
  float4 b = *(const float4*)(sp + 4);
  bf16x8 o;
  u16* op = (u16*)&o;
  op[0] = f2bf(a.x); op[1] = f2bf(a.y); op[2] = f2bf(a.z); op[3] = f2bf(a.w);
  op[4] = f2bf(b.x); op[5] = f2bf(b.y); op[6] = f2bf(b.z); op[7] = f2bf(b.w);
  *(bf16x8*)(d + (size_t)tid * 8) = o;
}

__global__ void zero16(uint4* __restrict__ p, int n4) {
  int i = blockIdx.x * blockDim.x + threadIdx.x;
  if (i < n4) p[i] = make_uint4(0u, 0u, 0u, 0u);
}

// h-state buffers are stored in A-fragment-packed order:
//   hP[parity][part(hi/lo)][m16(8)][kc(32)][lane(64)][8]
//   element (row,k): m16=row>>4, kc=k>>5, lane=((k>>3)&3)*16 + (row&15), j=k&7
// Plane stride (one parity+part): 8*32*64*8 = 131072 elems.
#define PS 131072

// Grid: 256 blocks x 1024 threads (16 waves/CU). wave w: q=w&1, mi=(w>>1)&1, kg=w>>2.
// blocks 0..127: layer0 (+linear on hsl==0); 128..255: layer1.
__global__ __launch_bounds__(1024, 1) void gru_main(
    const float* __restrict__ x,
    const float* __restrict__ b_ih0, const float* __restrict__ b_hh0,
    const float* __restrict__ b_ih1, const float* __restrict__ b_hh1,
    const float* __restrict__ b_lin,
    const u16* __restrict__ wih0p, const u16* __restrict__ whh0p,
    const u16* __restrict__ wih1p, const u16* __restrict__ whh1p,
    const u16* __restrict__ wlinp,
    u16* __restrict__ hA, u16* __restrict__ hB,
    float* __restrict__ out) {
  cg::grid_group grid = cg::this_grid();
  __shared__ float part[3][4][32][33];       // [kg-1][qty r,z,ni,nh][row32][col32(+1)]
  float* p2buf = (float*)part;               // linear-phase partials [3][32][65]

  const int blk  = blockIdx.x;
  const int tid  = threadIdx.x;
  const int w    = tid >> 6;
  const int lane = tid & 63;
  const int q    = w & 1;
  const int mi   = (w >> 1) & 1;
  const int kg   = w >> 2;         // 0..3, K-slice of 256
  const int ln   = lane & 15;
  const int lq   = lane >> 4;
  const int layer = blk >> 7;
  const int lb   = blk & 127;
  const int bg   = lb >> 5;        // batch group 0..3
  const int hsl  = lb & 31;        // hidden 32-col slice
  const int m0   = bg * 32;
  const int h0   = hsl * 32;
  const int m16  = bg * 2 + mi;
  const int col  = h0 + q * 16 + ln;
  const f32x4 vzero = {0.f, 0.f, 0.f, 0.f};

  // A-fragment base offset for this wave's (m16, kg) position
  const size_t aoff = (((size_t)m16 * 32 + kg * 8) * 64 + lane) * 8;
  // B-fragment offset helper for H-K matrices (nkc=32): gate g
  const size_t wo0 = (((size_t)(0 * 64 + hsl * 2 + q) * 32 + kg * 8) * 64 + lane) * 8;
  const size_t wo1 = (((size_t)(1 * 64 + hsl * 2 + q) * 32 + kg * 8) * 64 + lane) * 8;
  const size_t wo2 = (((size_t)(2 * 64 + hsl * 2 + q) * 32 + kg * 8) * 64 + lane) * 8;

  // packed h index for this lane's C-layout positions (phase C)
  const int lqA = q * 2 + (ln >> 3);
  const int jA  = ln & 7;

  if (layer == 0) {
    const float bir = b_ih0[col], biz = b_ih0[Hn + col], bin_ = b_ih0[2 * Hn + col];
    const float bhr = b_hh0[col], bhz = b_hh0[Hn + col], bhn  = b_hh0[2 * Hn + col];
    const u16* w0 = whh0p + wo0;
    const u16* w1 = whh0p + wo1;
    const u16* w2 = whh0p + wo2;
    const bool is_lin = (hsl == 0);
    float bl0 = 0.f, bl1 = 0.f;
    if (is_lin) { bl0 = b_lin[q * 32 + ln]; bl1 = b_lin[q * 32 + 16 + ln]; }

    for (int t = 0; t <= Tn + 1; ++t) {
      if (t < Tn) {
        const int rp = (t + 1) & 1;
        const int wp = t & 1;
        f32x4 accI[3] = {vzero, vzero, vzero};
        f32x4 accH[3] = {vzero, vzero, vzero};
        // x-gemm (K=64) only on kg==0 waves
        if (kg == 0) {
          const float* xr = x + ((size_t)t * Bn + (m0 + mi * 16 + ln)) * INn + lq * 8;
#pragma unroll
          for (int kc = 0; kc < 2; ++kc) {
            float4 v0 = *(const float4*)(xr + kc * 32);
            float4 v1 = *(const float4*)(xr + kc * 32 + 4);
            bf16x8 a;
            u16* ap = (u16*)&a;
            ap[0] = f2bf(v0.x); ap[1] = f2bf(v0.y); ap[2] = f2bf(v0.z); ap[3] = f2bf(v0.w);
            ap[4] = f2bf(v1.x); ap[5] = f2bf(v1.y); ap[6] = f2bf(v1.z); ap[7] = f2bf(v1.w);
            const size_t xo0 = (((size_t)(0 * 64 + hsl * 2 + q) * 2 + kc) * 64 + lane) * 8;
            const size_t xo1 = (((size_t)(1 * 64 + hsl * 2 + q) * 2 + kc) * 64 + lane) * 8;
            const size_t xo2 = (((size_t)(2 * 64 + hsl * 2 + q) * 2 + kc) * 64 + lane) * 8;
            accI[0] = mfma16(a, *(const bf16x8*)(wih0p + xo0), accI[0]);
            accI[1] = mfma16(a, *(const bf16x8*)(wih0p + xo1), accI[1]);
            accI[2] = mfma16(a, *(const bf16x8*)(wih0p + xo2), accI[2]);
          }
        }
        // gh = h_{t-1} @ whh0^T, this wave's K=256 slice
        const u16* ahp = hA + (size_t)(rp * 2 + 0) * PS + aoff;
        const u16* alp = hA + (size_t)(rp * 2 + 1) * PS + aoff;
#pragma unroll 2
        for (int kt = 0; kt < 8; ++kt) {
          const int o = kt * 512;
          bf16x8 Ah = *(const bf16x8*)(ahp + o);
          bf16x8 Al = *(const bf16x8*)(alp + o);
          bf16x8 B0 = *(const bf16x8*)(w0 + o);
          bf16x8 B1 = *(const bf16x8*)(w1 + o);
          bf16x8 B2 = *(const bf16x8*)(w2 + o);
          accH[0] = mfma16(Ah, B0, accH[0]);
          accH[1] = mfma16(Ah, B1, accH[1]);
          accH[2] = mfma16(Ah, B2, accH[2]);
          accH[0] = mfma16(Al, B0, accH[0]);
          accH[1] = mfma16(Al, B1, accH[1]);
          accH[2] = mfma16(Al, B2, accH[2]);
        }
        // phase B: kg>0 dump partials
        if (kg > 0) {
#pragma unroll
          for (int i = 0; i < 4; ++i) {
            const int r32 = mi * 16 + lq * 4 + i;
            const int c32 = q * 16 + ln;
            part[kg - 1][0][r32][c32] = accI[0][i] + accH[0][i];
            part[kg - 1][1][r32][c32] = accI[1][i] + accH[1][i];
            part[kg - 1][2][r32][c32] = accI[2][i];
            part[kg - 1][3][r32][c32] = accH[2][i];
          }
        }
        __syncthreads();
        // phase C: kg==0 reduces + nonlinearity + packed h write
        if (kg == 0) {
          const u16* rh = hA + (size_t)(rp * 2 + 0) * PS;
          const u16* rl = hA + (size_t)(rp * 2 + 1) * PS;
          u16* wh = hA + (size_t)(wp * 2 + 0) * PS;
          u16* wl = hA + (size_t)(wp * 2 + 1) * PS;
#pragma unroll
          for (int i = 0; i < 4; ++i) {
            const int r32 = mi * 16 + lq * 4 + i;
            const int c32 = q * 16 + ln;
            float rs = accI[0][i] + accH[0][i] + part[0][0][r32][c32] + part[1][0][r32][c32] + part[2][0][r32][c32];
            float zs = accI[1][i] + accH[1][i] + part[0][1][r32][c32] + part[1][1][r32][c32] + part[2][1][r32][c32];
            float ni = accI[2][i]               + part[0][2][r32][c32] + part[1][2][r32][c32] + part[2][2][r32][c32];
            float nh = accH[2][i]               + part[0][3][r32][c32] + part[1][3][r32][c32] + part[2][3][r32][c32];
            float r  = sigmoidf_(rs + bir + bhr);
            float z  = sigmoidf_(zs + biz + bhz);
            float nn = tanhf_(ni + bin_ + r * (nh + bhn));
            const size_t idx = (((size_t)m16 * 32 + hsl) * 64 + (lqA * 16 + lq * 4 + i)) * 8 + jA;
            float hp = bf2f(rh[idx]) + bf2f(rl[idx]);
            float hv = (1.0f - z) * nn + z * hp;
            u16 hh = f2bf(hv);
            wh[idx] = hh;
            wl[idx] = f2bf(hv - bf2f(hh));
          }
        }
      }
      // linear phase for the 4 lin blocks: out_{t-2} = h2_{t-2} @ wlin^T + b
      if (is_lin && t >= 2) {
        __syncthreads();  // LDS part buffer free for reuse
        const int s2 = t - 2;
        const int pp = s2 & 1;
        const u16* ah = hB + (size_t)(pp * 2 + 0) * PS + aoff;
        const u16* al = hB + (size_t)(pp * 2 + 1) * PS + aoff;
        const u16* L0 = wlinp + (((size_t)(q * 2 + 0) * 32 + kg * 8) * 64 + lane) * 8;
        const u16* L1 = wlinp + (((size_t)(q * 2 + 1) * 32 + kg * 8) * 64 + lane) * 8;
        f32x4 ac0 = vzero, ac1 = vzero;
#pragma unroll 2
        for (int kt = 0; kt < 8; ++kt) {
          const int o = kt * 512;
          bf16x8 Ah = *(const bf16x8*)(ah + o);
          bf16x8 Al = *(const bf16x8*)(al + o);
          bf16x8 B0 = *(const bf16x8*)(L0 + o);
          bf16x8 B1 = *(const bf16x8*)(L1 + o);
          ac0 = mfma16(Ah, B0, ac0);
          ac1 = mfma16(Ah, B1, ac1);
          ac0 = mfma16(Al, B0, ac0);
          ac1 = mfma16(Al, B1, ac1);
        }
        if (kg > 0) {
#pragma unroll
          for (int i = 0; i < 4; ++i) {
            const int r32 = mi * 16 + lq * 4 + i;
            p2buf[((kg - 1) * 32 + r32) * 65 + (q * 32 + ln)]      = ac0[i];
            p2buf[((kg - 1) * 32 + r32) * 65 + (q * 32 + 16 + ln)] = ac1[i];
          }
        }
        __syncthreads();
        if (kg == 0) {
#pragma unroll
          for (int i = 0; i < 4; ++i) {
            const int r32 = mi * 16 + lq * 4 + i;
            const int rowg = m0 + r32;
            float s0 = ac0[i], s1 = ac1[i];
#pragma unroll
            for (int p = 0; p < 3; ++p) {
              s0 += p2buf[(p * 32 + r32) * 65 + (q * 32 + ln)];
              s1 += p2buf[(p * 32 + r32) * 65 + (q * 32 + 16 + ln)];
            }
            float* orow = out + ((size_t)s2 * Bn + rowg) * 64;
            orow[q * 32 + ln]      = s0 + bl0;
            orow[q * 32 + 16 + ln] = s1 + bl1;
          }
        }
      }
      grid.sync();
    }
  } else {
    // ---------------- layer 1 : step s = t-1 ----------------
    const float bir = b_ih1[col], biz = b_ih1[Hn + col], bin_ = b_ih1[2 * Hn + col];
    const float bhr = b_hh1[col], bhz = b_hh1[Hn + col], bhn  = b_hh1[2 * Hn + col];
    const u16* wi0 = wih1p + wo0;
    const u16* wi1 = wih1p + wo1;
    const u16* wi2 = wih1p + wo2;
    const u16* w0  = whh1p + wo0;
    const u16* w1  = whh1p + wo1;
    const u16* w2  = whh1p + wo2;

    for (int t = 0; t <= Tn + 1; ++t) {
      if (t >= 1 && t <= Tn) {
        const int s  = t - 1;
        const int sp = s & 1;
        const int rp = (s + 1) & 1;
        const int wp = s & 1;
        f32x4 accI[3] = {vzero, vzero, vzero};
        f32x4 accH[3] = {vzero, vzero, vzero};
        const u16* a1h = hA + (size_t)(sp * 2 + 0) * PS + aoff;
        const u16* a1l = hA + (size_t)(sp * 2 + 1) * PS + aoff;
        const u16* a2h = hB + (size_t)(rp * 2 + 0) * PS + aoff;
        const u16* a2l = hB + (size_t)(rp * 2 + 1) * PS + aoff;
#pragma unroll 2
        for (int kt = 0; kt < 8; ++kt) {
          const int o = kt * 512;
          bf16x8 A1h = *(const bf16x8*)(a1h + o);
          bf16x8 A1l = *(const bf16x8*)(a1l + o);
          bf16x8 A2h = *(const bf16x8*)(a2h + o);
          bf16x8 A2l = *(const bf16x8*)(a2l + o);
          bf16x8 Bi0 = *(const bf16x8*)(wi0 + o);
          bf16x8 Bi1 = *(const bf16x8*)(wi1 + o);
          bf16x8 Bi2 = *(const bf16x8*)(wi2 + o);
          bf16x8 Bh0 = *(const bf16x8*)(w0 + o);
          bf16x8 Bh1 = *(const bf16x8*)(w1 + o);
          bf16x8 Bh2 = *(const bf16x8*)(w2 + o);
          accI[0] = mfma16(A1h, Bi0, accI[0]);
          accI[1] = mfma16(A1h, Bi1, accI[1]);
          accI[2] = mfma16(A1h, Bi2, accI[2]);
          accI[0] = mfma16(A1l, Bi0, accI[0]);
          accI[1] = mfma16(A1l, Bi1, accI[1]);
          accI[2] = mfma16(A1l, Bi2, accI[2]);
          accH[0] = mfma16(A2h, Bh0, accH[0]);
          accH[1] = mfma16(A2h, Bh1, accH[1]);
          accH[2] = mfma16(A2h, Bh2, accH[2]);
          accH[0] = mfma16(A2l, Bh0, accH[0]);
          accH[1] = mfma16(A2l, Bh1, accH[1]);
          accH[2] = mfma16(A2l, Bh2, accH[2]);
        }
        if (kg > 0) {
#pragma unroll
          for (int i = 0; i < 4; ++i) {
            const int r32 = mi * 16 + lq * 4 + i;
            const int c32 = q * 16 + ln;
            part[kg - 1][0][r32][c32] = accI[0][i] + accH[0][i];
            part[kg - 1][1][r32][c32] = accI[1][i] + accH[1][i];
            part[kg - 1][2][r32][c32] = accI[2][i];
            part[kg - 1][3][r32][c32] = accH[2][i];
          }
        }
        __syncthreads();
        if (kg == 0) {
          const u16* rh = hB + (size_t)(rp * 2 + 0) * PS;
          const u16* rl = hB + (size_t)(rp * 2 + 1) * PS;
          u16* wh = hB + (size_t)(wp * 2 + 0) * PS;
          u16* wl = hB + (size_t)(wp * 2 + 1) * PS;
#pragma unroll
          for (int i = 0; i < 4; ++i) {
            const int r32 = mi * 16 + lq * 4 + i;
            const int c32 = q * 16 + ln;
            float rs = accI[0][i] + accH[0][i] + part[0][0][r32][c32] + part[1][0][r32][c32] + part[2][0][r32][c32];
            float zs = accI[1][i] + accH[1][i] + part[0][1][r32][c32] + part[1][1][r32][c32] + part[2][1][r32][c32];
            float ni = accI[2][i]               + part[0][2][r32][c32] + part[1][2][r32][c32] + part[2][2][r32][c32];
            float nh = accH[2][i]               + part[0][3][r32][c32] + part[1][3][r32][c32] + part[2][3][r32][c32];
            float r  = sigmoidf_(rs + bir + bhr);
            float z  = sigmoidf_(zs + biz + bhz);
            float nn = tanhf_(ni + bin_ + r * (nh + bhn));
            const size_t idx = (((size_t)m16 * 32 + hsl) * 64 + (lqA * 16 + lq * 4 + i)) * 8 + jA;
            float hp = bf2f(rh[idx]) + bf2f(rl[idx]);
            float hv = (1.0f - z) * nn + z * hp;
            u16 hh = f2bf(hv);
            wh[idx] = hh;
            wl[idx] = f2bf(hv - bf2f(hh));
          }
        }
      }
      grid.sync();
    }
  }
}

extern "C" void kernel_launch(void* const* d_in, const int* in_sizes, int n_in,
                              void* d_out, int out_size, void* d_ws, size_t ws_size,
                              hipStream_t stream) {
  (void)in_sizes; (void)n_in; (void)out_size; (void)ws_size;
  const float* x     = (const float*)d_in[0];
  const float* wih0f = (const float*)d_in[1];
  const float* whh0f = (const float*)d_in[2];
  const float* bih0  = (const float*)d_in[3];
  const float* bhh0  = (const float*)d_in[4];
  const float* wih1f = (const float*)d_in[5];
  const float* whh1f = (const float*)d_in[6];
  const float* bih1  = (const float*)d_in[7];
  const float* bhh1  = (const float*)d_in[8];
  const float* wlinf = (const float*)d_in[9];
  const float* blin  = (const float*)d_in[10];
  float* out = (float*)d_out;

  char* w = (char*)d_ws;
  u16* whh0p = (u16*)w; w += (size_t)3072 * 1024 * 2;
  u16* wih1p = (u16*)w; w += (size_t)3072 * 1024 * 2;
  u16* whh1p = (u16*)w; w += (size_t)3072 * 1024 * 2;
  u16* wih0p = (u16*)w; w += (size_t)3072 * 64 * 2;
  u16* wlinp = (u16*)w; w += (size_t)64 * 1024 * 2;
  u16* hA    = (u16*)w; w += (size_t)4 * PS * 2;   // [parity][part] packed planes
  u16* hB    = (u16*)w; w += (size_t)4 * PS * 2;

  const int thr = 256;
  pack_w<<<(3072 * 1024 / 8 + thr - 1) / thr, thr, 0, stream>>>(whh0f, whh0p, 3072, 1024);
  pack_w<<<(3072 * 1024 / 8 + thr - 1) / thr, thr, 0, stream>>>(wih1f, wih1p, 3072, 1024);
  pack_w<<<(3072 * 1024 / 8 + thr - 1) / thr, thr, 0, stream>>>(whh1f, whh1p, 3072, 1024);
  pack_w<<<(3072 * 64 / 8 + thr - 1) / thr, thr, 0, stream>>>(wih0f, wih0p, 3072, 64);
  pack_w<<<(64 * 1024 / 8 + thr - 1) / thr, thr, 0, stream>>>(wlinf, wlinp, 64, 1024);
  const int n4 = (int)((size_t)8 * PS * 2 / 16);   // hA+hB contiguous, 2 MiB
  zero16<<<(n4 + thr - 1) / thr, thr, 0, stream>>>((uint4*)hA, n4);

  void* args[] = {(void*)&x,     (void*)&bih0,  (void*)&bhh0,  (void*)&bih1, (void*)&bhh1,
                  (void*)&blin,  (void*)&wih0p, (void*)&whh0p, (void*)&wih1p, (void*)&whh1p,
                  (void*)&wlinp, (void*)&hA,    (void*)&hB,    (void*)&out};
  hipLaunchCooperativeKernel((const void*)gru_main, dim3(256), dim3(1024), args, 0, stream);
}

// Round 3
// 21104.843 us; speedup vs baseline: 2.2094x; 2.2094x over previous
//
#include <hip/hip_runtime.h>
#include <hip/hip_cooperative_groups.h>

namespace cg = cooperative_groups;

#define Tn  512
#define Bn  128
#define INn 64
#define Hn  1024

typedef __attribute__((ext_vector_type(8))) short bf16x8;
typedef __attribute__((ext_vector_type(4))) float f32x4;
typedef unsigned short u16;

__device__ __forceinline__ u16 f2bf(float f) {
  unsigned u = __float_as_uint(f);
  unsigned r = (u + 0x7fffu + ((u >> 16) & 1u)) >> 16;
  return (u16)r;
}
__device__ __forceinline__ float bf2f(u16 h) {
  return __uint_as_float(((unsigned)h) << 16);
}
__device__ __forceinline__ float sigmoidf_(float x) {
  return 1.0f / (1.0f + __expf(-x));
}
__device__ __forceinline__ float tanhf_(float x) {
  float e = __expf(-2.0f * fabsf(x));
  float t = (1.0f - e) / (1.0f + e);
  return copysignf(t, x);
}
__device__ __forceinline__ f32x4 mfma16(bf16x8 a, bf16x8 b, f32x4 c) {
  return __builtin_amdgcn_mfma_f32_16x16x32_bf16(a, b, c, 0, 0, 0);
}
// packed h index: element (row, col) of a [128][1024] plane in A-fragment order
__device__ __forceinline__ size_t hidx(int row, int col) {
  return ((size_t)((row >> 4) * 32 + (col >> 5))) * 512 +
         ((((col >> 3) & 3) * 16 + (row & 15)) * 8) + (col & 7);
}

// Repack fp32 weights (R x K, row-major) into MFMA B-fragment order.
__global__ void pack_w(const float* __restrict__ s, u16* __restrict__ d, int R, int K) {
  int tid = blockIdx.x * blockDim.x + threadIdx.x;
  int total = (R * K) >> 3;
  if (tid >= total) return;
  int l = tid & 63;
  int ckc = tid >> 6;
  int nkc = K >> 5;
  int ct = ckc / nkc;
  int kc = ckc - ct * nkc;
  int row = ct * 16 + (l & 15);
  int k0 = kc * 32 + (l >> 4) * 8;
  const float* sp = s + (size_t)row * K + k0;
  float4 a = *(const float4*)sp;
  float4 b = *(const float4*)(sp + 4);
  bf16x8 o;
  u16* op = (u16*)&o;
  op[0] = f2bf(a.x); op[1] = f2bf(a.y); op[2] = f2bf(a.z); op[3] = f2bf(a.w);
  op[4] = f2bf(b.x); op[5] = f2bf(b.y); op[6] = f2bf(b.z); op[7] = f2bf(b.w);
  *(bf16x8*)(d + (size_t)tid * 8) = o;
}

__global__ void zero16(uint4* __restrict__ p, int n4) {
  int i = blockIdx.x * blockDim.x + threadIdx.x;
  if (i < n4) p[i] = make_uint4(0u, 0u, 0u, 0u);
}

#define PS 131072  // elements in one packed [128][1024] plane

// 256 blocks x 512 threads. blocks 0..127: layer0 (32c x 32r; hsl<4 also linear);
// blocks 128..255: layer1 (16c x 64r). Weights live in VGPRs across the t-loop.
__global__ __launch_bounds__(512, 2) void gru_main(
    const float* __restrict__ x,
    const float* __restrict__ b_ih0, const float* __restrict__ b_hh0,
    const float* __restrict__ b_ih1, const float* __restrict__ b_hh1,
    const float* __restrict__ b_lin,
    const u16* __restrict__ wih0p, const u16* __restrict__ whh0p,
    const u16* __restrict__ wih1p, const u16* __restrict__ whh1p,
    const u16* __restrict__ wlinp,
    u16* __restrict__ hA, u16* __restrict__ hB,
    float* __restrict__ out) {
  cg::grid_group grid = cg::this_grid();
  __shared__ float lds[15840];  // layer0: H[2][4][3][16][33]@0 + I[2][3][16][33]@12672
                                // layer1: P[2][8][3][16][17]@0 ; lin: [8][2][16][17]@0

  const int blk  = blockIdx.x;
  const int tid  = threadIdx.x;
  const int w    = tid >> 6;
  const int lane = tid & 63;
  const int ln   = lane & 15;
  const int lq   = lane >> 4;
  const int layer = blk >> 7;
  const int lb   = blk & 127;
  const f32x4 vz = {0.f, 0.f, 0.f, 0.f};

  if (layer == 0) {
    const int bg  = lb >> 5;       // batch group (32 rows)
    const int hsl = lb & 31;       // 32-col slice
    const int q   = w & 1;         // col half
    const int kg  = w >> 1;        // K slice (256)
    const int c16 = hsl * 2 + q;
    // ---- persistent weights ----
    bf16x8 W[3][8];
#pragma unroll
    for (int g = 0; g < 3; ++g)
#pragma unroll
      for (int kc = 0; kc < 8; ++kc)
        W[g][kc] = *(const bf16x8*)(whh0p + (((size_t)(g * 64 + c16) * 32 + kg * 8 + kc) * 64 + lane) * 8);
    bf16x8 Wx[3][2];
    if (kg == 0) {
#pragma unroll
      for (int g = 0; g < 3; ++g)
#pragma unroll
        for (int kc = 0; kc < 2; ++kc)
          Wx[g][kc] = *(const bf16x8*)(wih0p + (((size_t)(g * 64 + c16) * 2 + kc) * 64 + lane) * 8);
    }
    const bool is_lin = (hsl < 4);
    bf16x8 Wl[4];
    float Blin = 0.f;
    if (is_lin) {
#pragma unroll
      for (int kc = 0; kc < 4; ++kc)
        Wl[kc] = *(const bf16x8*)(wlinp + (((size_t)hsl * 32 + w * 4 + kc) * 64 + lane) * 8);
      Blin = b_lin[hsl * 16 + (tid & 15)];
    }
    // ---- reduce-phase constants (2 outputs / thread) ----
    const int rm  = tid >> 8;            // m tile 0/1
    const int rr  = (tid >> 4) & 15;     // row in tile
    const int rc2 = (tid & 15) * 2;      // col pair in 32
    const int ggr = bg * 32 + rm * 16 + rr;
    float Br[2], Bz[2], Bni[2], Bnh[2];
#pragma unroll
    for (int e = 0; e < 2; ++e) {
      const int gc = hsl * 32 + rc2 + e;
      Br[e]  = b_ih0[gc] + b_hh0[gc];
      Bz[e]  = b_ih0[Hn + gc] + b_hh0[Hn + gc];
      Bni[e] = b_ih0[2 * Hn + gc];
      Bnh[e] = b_hh0[2 * Hn + gc];
    }

    for (int t = 0; t <= Tn + 1; ++t) {
      if (t < Tn) {
        const int rp = (t + 1) & 1;
        const int wp = t & 1;
        const u16* Ahb = hA + (size_t)(rp * 2 + 0) * PS;
        const u16* Alb = hA + (size_t)(rp * 2 + 1) * PS;
#pragma unroll
        for (int m = 0; m < 2; ++m) {
          const int m16 = bg * 2 + m;
          f32x4 acc[3] = {vz, vz, vz};
          const size_t ab = ((size_t)m16 * 32 + kg * 8) * 512 + lane * 8;
#pragma unroll
          for (int kc = 0; kc < 8; ++kc) {
            bf16x8 ah = *(const bf16x8*)(Ahb + ab + kc * 512);
            bf16x8 al = *(const bf16x8*)(Alb + ab + kc * 512);
            acc[0] = mfma16(ah, W[0][kc], acc[0]);
            acc[1] = mfma16(ah, W[1][kc], acc[1]);
            acc[2] = mfma16(ah, W[2][kc], acc[2]);
            acc[0] = mfma16(al, W[0][kc], acc[0]);
            acc[1] = mfma16(al, W[1][kc], acc[1]);
            acc[2] = mfma16(al, W[2][kc], acc[2]);
          }
          float* Hp = lds + (size_t)(m * 4 + kg) * 3 * 528;
#pragma unroll
          for (int g = 0; g < 3; ++g)
#pragma unroll
            for (int i = 0; i < 4; ++i)
              Hp[g * 528 + (lq * 4 + i) * 33 + q * 16 + ln] = acc[g][i];
          if (kg == 0) {
            f32x4 ax[3] = {vz, vz, vz};
            const float* xr = x + ((size_t)t * Bn + bg * 32 + m * 16 + ln) * INn + lq * 8;
#pragma unroll
            for (int kc = 0; kc < 2; ++kc) {
              float4 v0 = *(const float4*)(xr + kc * 32);
              float4 v1 = *(const float4*)(xr + kc * 32 + 4);
              bf16x8 a;
              u16* ap = (u16*)&a;
              ap[0] = f2bf(v0.x); ap[1] = f2bf(v0.y); ap[2] = f2bf(v0.z); ap[3] = f2bf(v0.w);
              ap[4] = f2bf(v1.x); ap[5] = f2bf(v1.y); ap[6] = f2bf(v1.z); ap[7] = f2bf(v1.w);
              ax[0] = mfma16(a, Wx[0][kc], ax[0]);
              ax[1] = mfma16(a, Wx[1][kc], ax[1]);
              ax[2] = mfma16(a, Wx[2][kc], ax[2]);
            }
            float* Ip = lds + 12672 + (size_t)m * 3 * 528;
#pragma unroll
            for (int g = 0; g < 3; ++g)
#pragma unroll
              for (int i = 0; i < 4; ++i)
                Ip[g * 528 + (lq * 4 + i) * 33 + q * 16 + ln] = ax[g][i];
          }
        }
        __syncthreads();
        {
          const u16* rhp = Ahb;
          const u16* rlp = Alb;
          u16* whp = hA + (size_t)(wp * 2 + 0) * PS;
          u16* wlp = hA + (size_t)(wp * 2 + 1) * PS;
#pragma unroll
          for (int e = 0; e < 2; ++e) {
            const int c = rc2 + e;
            const int gc = hsl * 32 + c;
            const float* Ip = lds + 12672 + (size_t)rm * 3 * 528 + rr * 33 + c;
            float I0 = Ip[0], I1 = Ip[528], I2 = Ip[1056];
            float H0 = 0.f, H1 = 0.f, H2 = 0.f;
#pragma unroll
            for (int kgi = 0; kgi < 4; ++kgi) {
              const float* Hp = lds + (size_t)(rm * 4 + kgi) * 3 * 528 + rr * 33 + c;
              H0 += Hp[0]; H1 += Hp[528]; H2 += Hp[1056];
            }
            float r  = sigmoidf_(I0 + H0 + Br[e]);
            float zz = sigmoidf_(I1 + H1 + Bz[e]);
            float nn = tanhf_(I2 + Bni[e] + r * (H2 + Bnh[e]));
            const size_t idx = hidx(ggr, gc);
            float hp = bf2f(rhp[idx]) + bf2f(rlp[idx]);
            float hv = (1.0f - zz) * nn + zz * hp;
            u16 hh = f2bf(hv);
            whp[idx] = hh;
            wlp[idx] = f2bf(hv - bf2f(hh));
          }
        }
      }
      if (is_lin && t >= 2) {
        const int s2 = t - 2;
        const int p2 = s2 & 1;
        const u16* Bh = hB + (size_t)(p2 * 2 + 0) * PS;
        const u16* Bl = hB + (size_t)(p2 * 2 + 1) * PS;
        f32x4 la[2] = {vz, vz};
#pragma unroll
        for (int m = 0; m < 2; ++m) {
          const int m16 = bg * 2 + m;
          const size_t ab = ((size_t)m16 * 32 + w * 4) * 512 + lane * 8;
#pragma unroll
          for (int kc = 0; kc < 4; ++kc) {
            bf16x8 ah = *(const bf16x8*)(Bh + ab + kc * 512);
            bf16x8 al = *(const bf16x8*)(Bl + ab + kc * 512);
            la[m] = mfma16(ah, Wl[kc], la[m]);
            la[m] = mfma16(al, Wl[kc], la[m]);
          }
        }
        __syncthreads();  // H region reads (GRU reduce) complete
#pragma unroll
        for (int m = 0; m < 2; ++m)
#pragma unroll
          for (int i = 0; i < 4; ++i)
            lds[((w * 2 + m) * 16 + lq * 4 + i) * 17 + ln] = la[m][i];
        __syncthreads();
        {
          const int lm = tid >> 8, lr = (tid >> 4) & 15, lc = tid & 15;
          float s = Blin;
#pragma unroll
          for (int w8 = 0; w8 < 8; ++w8)
            s += lds[((w8 * 2 + lm) * 16 + lr) * 17 + lc];
          out[((size_t)s2 * Bn + bg * 32 + lm * 16 + lr) * 64 + hsl * 16 + lc] = s;
        }
      }
      grid.sync();
    }
  } else {
    // ---------------- layer 1 ----------------
    const int cs  = lb >> 1;       // 16-col slice 0..63
    const int rh  = lb & 1;        // 64-row half
    const int side = w >> 2;       // 0: wih1 (A=h1), 1: whh1 (A=h2)
    const int ks  = w & 3;         // K slice (256) within side
    const u16* wsrc = side ? whh1p : wih1p;
    bf16x8 W[3][8];
#pragma unroll
    for (int g = 0; g < 3; ++g)
#pragma unroll
      for (int kc = 0; kc < 8; ++kc)
        W[g][kc] = *(const bf16x8*)(wsrc + (((size_t)(g * 64 + cs) * 32 + ks * 8 + kc) * 64 + lane) * 8);
    const int rm = tid >> 8;
    const int rr = (tid >> 4) & 15;
    const int rc = tid & 15;
    const int ggc = cs * 16 + rc;
    const float Br  = b_ih1[ggc] + b_hh1[ggc];
    const float Bz  = b_ih1[Hn + ggc] + b_hh1[Hn + ggc];
    const float Bni = b_ih1[2 * Hn + ggc];
    const float Bnh = b_hh1[2 * Hn + ggc];

    for (int t = 0; t <= Tn + 1; ++t) {
      if (t >= 1 && t <= Tn) {
        const int s   = t - 1;
        const int sp  = s & 1;   // h1_s parity
        const int rp2 = t & 1;   // h2_{s-1} parity
        const int wp2 = s & 1;
        const u16* Ahb = side ? (hB + (size_t)(rp2 * 2 + 0) * PS) : (hA + (size_t)(sp * 2 + 0) * PS);
        const u16* Alb = side ? (hB + (size_t)(rp2 * 2 + 1) * PS) : (hA + (size_t)(sp * 2 + 1) * PS);
        const u16* rhp = hB + (size_t)(rp2 * 2 + 0) * PS;
        const u16* rlp = hB + (size_t)(rp2 * 2 + 1) * PS;
        u16* whp = hB + (size_t)(wp2 * 2 + 0) * PS;
        u16* wlp = hB + (size_t)(wp2 * 2 + 1) * PS;
#pragma unroll
        for (int round = 0; round < 2; ++round) {
#pragma unroll
          for (int m = 0; m < 2; ++m) {
            const int m16 = rh * 4 + round * 2 + m;
            f32x4 acc[3] = {vz, vz, vz};
            const size_t ab = ((size_t)m16 * 32 + ks * 8) * 512 + lane * 8;
#pragma unroll
            for (int kc = 0; kc < 8; ++kc) {
              bf16x8 ah = *(const bf16x8*)(Ahb + ab + kc * 512);
              bf16x8 al = *(const bf16x8*)(Alb + ab + kc * 512);
              acc[0] = mfma16(ah, W[0][kc], acc[0]);
              acc[1] = mfma16(ah, W[1][kc], acc[1]);
              acc[2] = mfma16(ah, W[2][kc], acc[2]);
              acc[0] = mfma16(al, W[0][kc], acc[0]);
              acc[1] = mfma16(al, W[1][kc], acc[1]);
              acc[2] = mfma16(al, W[2][kc], acc[2]);
            }
#pragma unroll
            for (int g = 0; g < 3; ++g)
#pragma unroll
              for (int i = 0; i < 4; ++i)
                lds[(((m * 8 + w) * 3 + g) * 16 + lq * 4 + i) * 17 + ln] = acc[g][i];
          }
          __syncthreads();
          {
            float I0 = 0.f, I1 = 0.f, I2 = 0.f, H0 = 0.f, H1 = 0.f, H2 = 0.f;
#pragma unroll
            for (int wi = 0; wi < 4; ++wi) {
              const float* P = lds + (size_t)((rm * 8 + wi) * 3) * 272 + rr * 17 + rc;
              I0 += P[0]; I1 += P[272]; I2 += P[544];
            }
#pragma unroll
            for (int wi = 4; wi < 8; ++wi) {
              const float* P = lds + (size_t)((rm * 8 + wi) * 3) * 272 + rr * 17 + rc;
              H0 += P[0]; H1 += P[272]; H2 += P[544];
            }
            float r  = sigmoidf_(I0 + H0 + Br);
            float zz = sigmoidf_(I1 + H1 + Bz);
            float nn = tanhf_(I2 + Bni + r * (H2 + Bnh));
            const int gr = rh * 64 + (round * 2 + rm) * 16 + rr;
            const size_t idx = hidx(gr, ggc);
            float hp = bf2f(rhp[idx]) + bf2f(rlp[idx]);
            float hv = (1.0f - zz) * nn + zz * hp;
            u16 hh = f2bf(hv);
            whp[idx] = hh;
            wlp[idx] = f2bf(hv - bf2f(hh));
          }
          __syncthreads();
        }
      }
      grid.sync();
    }
  }
}

extern "C" void kernel_launch(void* const* d_in, const int* in_sizes, int n_in,
                              void* d_out, int out_size, void* d_ws, size_t ws_size,
                              hipStream_t stream) {
  (void)in_sizes; (void)n_in; (void)out_size; (void)ws_size;
  const float* x     = (const float*)d_in[0];
  const float* wih0f = (const float*)d_in[1];
  const float* whh0f = (const float*)d_in[2];
  const float* bih0  = (const float*)d_in[3];
  const float* bhh0  = (const float*)d_in[4];
  const float* wih1f = (const float*)d_in[5];
  const float* whh1f = (const float*)d_in[6];
  const float* bih1  = (const float*)d_in[7];
  const float* bhh1  = (const float*)d_in[8];
  const float* wlinf = (const float*)d_in[9];
  const float* blin  = (const float*)d_in[10];
  float* out = (float*)d_out;

  char* w = (char*)d_ws;
  u16* whh0p = (u16*)w; w += (size_t)3072 * 1024 * 2;
  u16* wih1p = (u16*)w; w += (size_t)3072 * 1024 * 2;
  u16* whh1p = (u16*)w; w += (size_t)3072 * 1024 * 2;
  u16* wih0p = (u16*)w; w += (size_t)3072 * 64 * 2;
  u16* wlinp = (u16*)w; w += (size_t)64 * 1024 * 2;
  u16* hA    = (u16*)w; w += (size_t)4 * PS * 2;
  u16* hB    = (u16*)w; w += (size_t)4 * PS * 2;

  const int thr = 256;
  pack_w<<<(3072 * 1024 / 8 + thr - 1) / thr, thr, 0, stream>>>(whh0f, whh0p, 3072, 1024);
  pack_w<<<(3072 * 1024 / 8 + thr - 1) / thr, thr, 0, stream>>>(wih1f, wih1p, 3072, 1024);
  pack_w<<<(3072 * 1024 / 8 + thr - 1) / thr, thr, 0, stream>>>(whh1f, whh1p, 3072, 1024);
  pack_w<<<(3072 * 64 / 8 + thr - 1) / thr, thr, 0, stream>>>(wih0f, wih0p, 3072, 64);
  pack_w<<<(64 * 1024 / 8 + thr - 1) / thr, thr, 0, stream>>>(wlinf, wlinp, 64, 1024);
  const int n4 = (int)((size_t)8 * PS * 2 / 16);
  zero16<<<(n4 + thr - 1) / thr, thr, 0, stream>>>((uint4*)hA, n4);

  void* args[] = {(void*)&x,     (void*)&bih0,  (void*)&bhh0,  (void*)&bih1,  (void*)&bhh1,
                  (void*)&blin,  (void*)&wih0p, (void*)&whh0p, (void*)&wih1p, (void*)&whh1p,
                  (void*)&wlinp, (void*)&hA,    (void*)&hB,    (void*)&out};
  hipLaunchCooperativeKernel((const void*)gru_main, dim3(256), dim3(512), args, 0, stream);
}

// Round 4
// 11347.683 us; speedup vs baseline: 4.1092x; 1.8598x over previous
//
#include <hip/hip_runtime.h>

#define Tn  512
#define Bn  128
#define INn 64
#define Hn  1024

typedef __attribute__((ext_vector_type(8))) short bf16x8;
typedef __attribute__((ext_vector_type(4))) float f32x4;
typedef unsigned short u16;

#define AGENT __HIP_MEMORY_SCOPE_AGENT

__device__ __forceinline__ u16 f2bf(float f) {
  unsigned u = __float_as_uint(f);
  unsigned r = (u + 0x7fffu + ((u >> 16) & 1u)) >> 16;
  return (u16)r;
}
__device__ __forceinline__ float bf2f(u16 h) {
  return __uint_as_float(((unsigned)h) << 16);
}
__device__ __forceinline__ float sigmoidf_(float x) {
  return 1.0f / (1.0f + __expf(-x));
}
__device__ __forceinline__ float tanhf_(float x) {
  float e = __expf(-2.0f * fabsf(x));
  float t = (1.0f - e) / (1.0f + e);
  return copysignf(t, x);
}
__device__ __forceinline__ f32x4 mfma16(bf16x8 a, bf16x8 b, f32x4 c) {
  return __builtin_amdgcn_mfma_f32_16x16x32_bf16(a, b, c, 0, 0, 0);
}
__device__ __forceinline__ size_t hidx(int row, int col) {
  return ((size_t)((row >> 4) * 32 + (col >> 5))) * 512 +
         ((((col >> 3) & 3) * 16 + (row & 15)) * 8) + (col & 7);
}
// relaxed spin until *p >= v, then one acquire load (L2 inv once, not per poll)
__device__ __forceinline__ void spin_ge(int* p, int v) {
  while (__hip_atomic_load(p, __ATOMIC_RELAXED, AGENT) < v)
    __builtin_amdgcn_s_sleep(1);
  (void)__hip_atomic_load(p, __ATOMIC_ACQUIRE, AGENT);
}

__global__ void pack_w(const float* __restrict__ s, u16* __restrict__ d, int R, int K) {
  int tid = blockIdx.x * blockDim.x + threadIdx.x;
  int total = (R * K) >> 3;
  if (tid >= total) return;
  int l = tid & 63;
  int ckc = tid >> 6;
  int nkc = K >> 5;
  int ct = ckc / nkc;
  int kc = ckc - ct * nkc;
  int row = ct * 16 + (l & 15);
  int k0 = kc * 32 + (l >> 4) * 8;
  const float* sp = s + (size_t)row * K + k0;
  float4 a = *(const float4*)sp;
  float4 b = *(const float4*)(sp + 4);
  bf16x8 o;
  u16* op = (u16*)&o;
  op[0] = f2bf(a.x); op[1] = f2bf(a.y); op[2] = f2bf(a.z); op[3] = f2bf(a.w);
  op[4] = f2bf(b.x); op[5] = f2bf(b.y); op[6] = f2bf(b.z); op[7] = f2bf(b.w);
  *(bf16x8*)(d + (size_t)tid * 8) = o;
}

__global__ void zero16(uint4* __restrict__ p, int n4) {
  int i = blockIdx.x * blockDim.x + threadIdx.x;
  if (i < n4) p[i] = make_uint4(0u, 0u, 0u, 0u);
}

#define PS 131072  // one packed [128][1024] plane (elements)
// h ring: [slot(4)][part hi/lo(2)][PS]; step s lives in slot s&3.

// flag offsets (ints, padded 128B apart)
#define F_BAR0(bg) (32 * (bg))
#define F_STEP0(bg) (128 + 32 * (bg))
#define F_BAR1(rh) (256 + 32 * (rh))
#define F_STEP1(rh) (320 + 32 * (rh))
#define F_LINPROG 384

__global__ __launch_bounds__(512, 2) void gru_main(
    const float* __restrict__ x,
    const float* __restrict__ b_ih0, const float* __restrict__ b_hh0,
    const float* __restrict__ b_ih1, const float* __restrict__ b_hh1,
    const float* __restrict__ b_lin,
    const u16* __restrict__ wih0p, const u16* __restrict__ whh0p,
    const u16* __restrict__ wih1p, const u16* __restrict__ whh1p,
    const u16* __restrict__ wlinp,
    u16* __restrict__ hA, u16* __restrict__ hB,
    float* __restrict__ out, int* __restrict__ flags) {
  __shared__ float lds[16320];  // layer0: H[2][4][3][16][34]@0 + I[2][3][16][34]@13056
                                // layer1: P[2][8][3][16][20]@0 ; lin: [8][2][16][20]@0

  const int blk  = blockIdx.x;
  const int tid  = threadIdx.x;
  const int w    = tid >> 6;
  const int lane = tid & 63;
  const int ln   = lane & 15;
  const int lq   = lane >> 4;
  const int layer = blk >> 7;
  const int lb   = blk & 127;
  const f32x4 vz = {0.f, 0.f, 0.f, 0.f};

  if (layer == 0) {
    const int bg  = lb >> 5;
    const int hsl = lb & 31;
    const int q   = w & 1;
    const int kg  = w >> 1;
    const int c16 = hsl * 2 + q;
    bf16x8 W[3][8];
#pragma unroll
    for (int g = 0; g < 3; ++g)
#pragma unroll
      for (int kc = 0; kc < 8; ++kc)
        W[g][kc] = *(const bf16x8*)(whh0p + (((size_t)(g * 64 + c16) * 32 + kg * 8 + kc) * 64 + lane) * 8);
    bf16x8 Wx[3][2];
    if (kg == 0) {
#pragma unroll
      for (int g = 0; g < 3; ++g)
#pragma unroll
        for (int kc = 0; kc < 2; ++kc)
          Wx[g][kc] = *(const bf16x8*)(wih0p + (((size_t)(g * 64 + c16) * 2 + kc) * 64 + lane) * 8);
    }
    const bool is_lin = (hsl < 4);
    bf16x8 Wl[4];
    float Blin = 0.f;
    if (is_lin) {
#pragma unroll
      for (int kc = 0; kc < 4; ++kc)
        Wl[kc] = *(const bf16x8*)(wlinp + (((size_t)hsl * 32 + w * 4 + kc) * 64 + lane) * 8);
      Blin = b_lin[hsl * 16 + (tid & 15)];
    }
    const int rm  = tid >> 8;
    const int rr  = (tid >> 4) & 15;
    const int rc2 = (tid & 15) * 2;
    const int ggr = bg * 32 + rm * 16 + rr;
    float Br[2], Bz[2], Bni[2], Bnh[2];
#pragma unroll
    for (int e = 0; e < 2; ++e) {
      const int gc = hsl * 32 + rc2 + e;
      Br[e]  = b_ih0[gc] + b_hh0[gc];
      Bz[e]  = b_ih0[Hn + gc] + b_hh0[Hn + gc];
      Bni[e] = b_ih0[2 * Hn + gc];
      Bnh[e] = b_hh0[2 * Hn + gc];
    }

    for (int t = 0; t <= Tn + 1; ++t) {
      if (t < Tn) {
        if (t > 0 && tid == 0) spin_ge(flags + F_BAR0(bg), 32 * t);  // group done t-1
        __syncthreads();
        const int rs = (t + 3) & 3;
        const int ws_ = t & 3;
        const u16* Ahb = hA + (size_t)(rs * 2 + 0) * PS;
        const u16* Alb = hA + (size_t)(rs * 2 + 1) * PS;
#pragma unroll
        for (int m = 0; m < 2; ++m) {
          const int m16 = bg * 2 + m;
          f32x4 acc[3] = {vz, vz, vz};
          const size_t ab = ((size_t)m16 * 32 + kg * 8) * 512 + lane * 8;
#pragma unroll
          for (int kc = 0; kc < 8; ++kc) {
            bf16x8 ah = *(const bf16x8*)(Ahb + ab + kc * 512);
            bf16x8 al = *(const bf16x8*)(Alb + ab + kc * 512);
            acc[0] = mfma16(ah, W[0][kc], acc[0]);
            acc[1] = mfma16(ah, W[1][kc], acc[1]);
            acc[2] = mfma16(ah, W[2][kc], acc[2]);
            acc[0] = mfma16(al, W[0][kc], acc[0]);
            acc[1] = mfma16(al, W[1][kc], acc[1]);
            acc[2] = mfma16(al, W[2][kc], acc[2]);
          }
          float* Hp = lds + (size_t)(m * 4 + kg) * 1632;
#pragma unroll
          for (int g = 0; g < 3; ++g)
#pragma unroll
            for (int i = 0; i < 4; ++i)
              Hp[g * 544 + (lq * 4 + i) * 34 + q * 16 + ln] = acc[g][i];
          if (kg == 0) {
            f32x4 ax[3] = {vz, vz, vz};
            const float* xr = x + ((size_t)t * Bn + bg * 32 + m * 16 + ln) * INn + lq * 8;
#pragma unroll
            for (int kc = 0; kc < 2; ++kc) {
              float4 v0 = *(const float4*)(xr + kc * 32);
              float4 v1 = *(const float4*)(xr + kc * 32 + 4);
              bf16x8 a;
              u16* ap = (u16*)&a;
              ap[0] = f2bf(v0.x); ap[1] = f2bf(v0.y); ap[2] = f2bf(v0.z); ap[3] = f2bf(v0.w);
              ap[4] = f2bf(v1.x); ap[5] = f2bf(v1.y); ap[6] = f2bf(v1.z); ap[7] = f2bf(v1.w);
              ax[0] = mfma16(a, Wx[0][kc], ax[0]);
              ax[1] = mfma16(a, Wx[1][kc], ax[1]);
              ax[2] = mfma16(a, Wx[2][kc], ax[2]);
            }
            float* Ip = lds + 13056 + (size_t)m * 1632;
#pragma unroll
            for (int g = 0; g < 3; ++g)
#pragma unroll
              for (int i = 0; i < 4; ++i)
                Ip[g * 544 + (lq * 4 + i) * 34 + q * 16 + ln] = ax[g][i];
          }
        }
        __syncthreads();
        if (tid == 0 && t >= 4) spin_ge(flags + F_STEP1(bg >> 1), t - 3);  // h0 ring backpressure
        __syncthreads();
        {
          const u16* rhp = Ahb;
          const u16* rlp = Alb;
          u16* whp = hA + (size_t)(ws_ * 2 + 0) * PS;
          u16* wlp = hA + (size_t)(ws_ * 2 + 1) * PS;
#pragma unroll
          for (int e = 0; e < 2; ++e) {
            const int c = rc2 + e;
            const int gc = hsl * 32 + c;
            const float* Ip = lds + 13056 + (size_t)rm * 1632 + rr * 34 + c;
            float I0 = Ip[0], I1 = Ip[544], I2 = Ip[1088];
            float H0 = 0.f, H1 = 0.f, H2 = 0.f;
#pragma unroll
            for (int kgi = 0; kgi < 4; ++kgi) {
              const float* Hp = lds + (size_t)(rm * 4 + kgi) * 1632 + rr * 34 + c;
              H0 += Hp[0]; H1 += Hp[544]; H2 += Hp[1088];
            }
            float r  = sigmoidf_(I0 + H0 + Br[e]);
            float zz = sigmoidf_(I1 + H1 + Bz[e]);
            float nn = tanhf_(I2 + Bni[e] + r * (H2 + Bnh[e]));
            const size_t idx = hidx(ggr, gc);
            float hp = bf2f(rhp[idx]) + bf2f(rlp[idx]);
            float hv = (1.0f - zz) * nn + zz * hp;
            u16 hh = f2bf(hv);
            whp[idx] = hh;
            wlp[idx] = f2bf(hv - bf2f(hh));
          }
        }
        __syncthreads();  // all h0_t stores drained (vmcnt) before release
        if (tid == 0) {
          __hip_atomic_fetch_add(flags + F_BAR0(bg), 1, __ATOMIC_RELEASE, AGENT);
          if (hsl == 31) {  // designated: publish group progress for layer1
            spin_ge(flags + F_BAR0(bg), 32 * (t + 1));
            __hip_atomic_store(flags + F_STEP0(bg), t + 1, __ATOMIC_RELEASE, AGENT);
          }
        }
      }
      if (is_lin && t >= 2) {
        const int s2 = t - 2;
        if (tid == 0) spin_ge(flags + F_STEP1(bg >> 1), t - 1);  // h2_{t-2} ready
        __syncthreads();
        const int p2 = s2 & 3;
        const u16* Bh = hB + (size_t)(p2 * 2 + 0) * PS;
        const u16* Bl = hB + (size_t)(p2 * 2 + 1) * PS;
        f32x4 la[2] = {vz, vz};
#pragma unroll
        for (int m = 0; m < 2; ++m) {
          const int m16 = bg * 2 + m;
          const size_t ab = ((size_t)m16 * 32 + w * 4) * 512 + lane * 8;
#pragma unroll
          for (int kc = 0; kc < 4; ++kc) {
            bf16x8 ah = *(const bf16x8*)(Bh + ab + kc * 512);
            bf16x8 al = *(const bf16x8*)(Bl + ab + kc * 512);
            la[m] = mfma16(ah, Wl[kc], la[m]);
            la[m] = mfma16(al, Wl[kc], la[m]);
          }
        }
        __syncthreads();
#pragma unroll
        for (int m = 0; m < 2; ++m)
#pragma unroll
          for (int i = 0; i < 4; ++i)
            lds[((w * 2 + m) * 16 + lq * 4 + i) * 20 + ln] = la[m][i];
        __syncthreads();
        {
          const int lm = tid >> 8, lr = (tid >> 4) & 15, lc = tid & 15;
          float s = Blin;
#pragma unroll
          for (int w8 = 0; w8 < 8; ++w8)
            s += lds[((w8 * 2 + lm) * 16 + lr) * 20 + lc];
          out[((size_t)s2 * Bn + bg * 32 + lm * 16 + lr) * 64 + hsl * 16 + lc] = s;
        }
        __syncthreads();
        if (tid == 0)
          __hip_atomic_fetch_add(flags + F_LINPROG, 1, __ATOMIC_RELEASE, AGENT);
      }
    }
  } else {
    // ---------------- layer 1 ----------------
    const int cs  = lb >> 1;
    const int rh  = lb & 1;
    const int side = w >> 2;
    const int ks  = w & 3;
    const u16* wsrc = side ? whh1p : wih1p;
    bf16x8 W[3][8];
#pragma unroll
    for (int g = 0; g < 3; ++g)
#pragma unroll
      for (int kc = 0; kc < 8; ++kc)
        W[g][kc] = *(const bf16x8*)(wsrc + (((size_t)(g * 64 + cs) * 32 + ks * 8 + kc) * 64 + lane) * 8);
    const int rm = tid >> 8;
    const int rr = (tid >> 4) & 15;
    const int rc = tid & 15;
    const int ggc = cs * 16 + rc;
    const float Br  = b_ih1[ggc] + b_hh1[ggc];
    const float Bz  = b_ih1[Hn + ggc] + b_hh1[Hn + ggc];
    const float Bni = b_ih1[2 * Hn + ggc];
    const float Bnh = b_hh1[2 * Hn + ggc];

    for (int s = 0; s < Tn; ++s) {
      if (tid == 0) {
        if (s > 0) spin_ge(flags + F_BAR1(rh), 64 * s);       // group done s-1
        spin_ge(flags + F_STEP0(2 * rh), s + 1);              // h1_s ready
        spin_ge(flags + F_STEP0(2 * rh + 1), s + 1);
        if (s >= 4) spin_ge(flags + F_LINPROG, 16 * (s - 3)); // h2 ring backpressure
      }
      __syncthreads();
      const int ss = s & 3;
      const int rs = (s + 3) & 3;
      const u16* A1h = hA + (size_t)(ss * 2 + 0) * PS;
      const u16* A1l = hA + (size_t)(ss * 2 + 1) * PS;
      const u16* A2h = hB + (size_t)(rs * 2 + 0) * PS;
      const u16* A2l = hB + (size_t)(rs * 2 + 1) * PS;
      u16* whp = hB + (size_t)(ss * 2 + 0) * PS;
      u16* wlp = hB + (size_t)(ss * 2 + 1) * PS;
      const u16* Ahb = side ? A2h : A1h;
      const u16* Alb = side ? A2l : A1l;
#pragma unroll
      for (int round = 0; round < 2; ++round) {
#pragma unroll
        for (int m = 0; m < 2; ++m) {
          const int m16 = rh * 4 + round * 2 + m;
          f32x4 acc[3] = {vz, vz, vz};
          const size_t ab = ((size_t)m16 * 32 + ks * 8) * 512 + lane * 8;
#pragma unroll
          for (int kc = 0; kc < 8; ++kc) {
            bf16x8 ah = *(const bf16x8*)(Ahb + ab + kc * 512);
            bf16x8 al = *(const bf16x8*)(Alb + ab + kc * 512);
            acc[0] = mfma16(ah, W[0][kc], acc[0]);
            acc[1] = mfma16(ah, W[1][kc], acc[1]);
            acc[2] = mfma16(ah, W[2][kc], acc[2]);
            acc[0] = mfma16(al, W[0][kc], acc[0]);
            acc[1] = mfma16(al, W[1][kc], acc[1]);
            acc[2] = mfma16(al, W[2][kc], acc[2]);
          }
#pragma unroll
          for (int g = 0; g < 3; ++g)
#pragma unroll
            for (int i = 0; i < 4; ++i)
              lds[((m * 8 + w) * 3 + g) * 320 + (lq * 4 + i) * 20 + ln] = acc[g][i];
        }
        __syncthreads();
        {
          float I0 = 0.f, I1 = 0.f, I2 = 0.f, H0 = 0.f, H1 = 0.f, H2 = 0.f;
#pragma unroll
          for (int wi = 0; wi < 4; ++wi) {
            const float* P = lds + ((rm * 8 + wi) * 3) * 320 + rr * 20 + rc;
            I0 += P[0]; I1 += P[320]; I2 += P[640];
          }
#pragma unroll
          for (int wi = 4; wi < 8; ++wi) {
            const float* P = lds + ((rm * 8 + wi) * 3) * 320 + rr * 20 + rc;
            H0 += P[0]; H1 += P[320]; H2 += P[640];
          }
          float r  = sigmoidf_(I0 + H0 + Br);
          float zz = sigmoidf_(I1 + H1 + Bz);
          float nn = tanhf_(I2 + Bni + r * (H2 + Bnh));
          const int gr = rh * 64 + (round * 2 + rm) * 16 + rr;
          const size_t idx = hidx(gr, ggc);
          float hp = bf2f(A2h[idx]) + bf2f(A2l[idx]);
          float hv = (1.0f - zz) * nn + zz * hp;
          u16 hh = f2bf(hv);
          whp[idx] = hh;
          wlp[idx] = f2bf(hv - bf2f(hh));
        }
        __syncthreads();
      }
      if (tid == 0) {
        __hip_atomic_fetch_add(flags + F_BAR1(rh), 1, __ATOMIC_RELEASE, AGENT);
        if (cs == 63) {  // designated: publish progress for lin + layer0 backpressure
          spin_ge(flags + F_BAR1(rh), 64 * (s + 1));
          __hip_atomic_store(flags + F_STEP1(rh), s + 1, __ATOMIC_RELEASE, AGENT);
        }
      }
    }
  }
}

extern "C" void kernel_launch(void* const* d_in, const int* in_sizes, int n_in,
                              void* d_out, int out_size, void* d_ws, size_t ws_size,
                              hipStream_t stream) {
  (void)in_sizes; (void)n_in; (void)out_size; (void)ws_size;
  const float* x     = (const float*)d_in[0];
  const float* wih0f = (const float*)d_in[1];
  const float* whh0f = (const float*)d_in[2];
  const float* bih0  = (const float*)d_in[3];
  const float* bhh0  = (const float*)d_in[4];
  const float* wih1f = (const float*)d_in[5];
  const float* whh1f = (const float*)d_in[6];
  const float* bih1  = (const float*)d_in[7];
  const float* bhh1  = (const float*)d_in[8];
  const float* wlinf = (const float*)d_in[9];
  const float* blin  = (const float*)d_in[10];
  float* out = (float*)d_out;

  char* w = (char*)d_ws;
  u16* whh0p = (u16*)w; w += (size_t)3072 * 1024 * 2;
  u16* wih1p = (u16*)w; w += (size_t)3072 * 1024 * 2;
  u16* whh1p = (u16*)w; w += (size_t)3072 * 1024 * 2;
  u16* wih0p = (u16*)w; w += (size_t)3072 * 64 * 2;
  u16* wlinp = (u16*)w; w += (size_t)64 * 1024 * 2;
  u16* hA    = (u16*)w; w += (size_t)4 * 2 * PS * 2;  // ring depth 4, hi/lo
  u16* hB    = (u16*)w; w += (size_t)4 * 2 * PS * 2;
  int* flags = (int*)w; w += 2048;

  const int thr = 256;
  pack_w<<<(3072 * 1024 / 8 + thr - 1) / thr, thr, 0, stream>>>(whh0f, whh0p, 3072, 1024);
  pack_w<<<(3072 * 1024 / 8 + thr - 1) / thr, thr, 0, stream>>>(wih1f, wih1p, 3072, 1024);
  pack_w<<<(3072 * 1024 / 8 + thr - 1) / thr, thr, 0, stream>>>(whh1f, whh1p, 3072, 1024);
  pack_w<<<(3072 * 64 / 8 + thr - 1) / thr, thr, 0, stream>>>(wih0f, wih0p, 3072, 64);
  pack_w<<<(64 * 1024 / 8 + thr - 1) / thr, thr, 0, stream>>>(wlinf, wlinp, 64, 1024);
  // zero hA + hB + flags (contiguous: 8MB + 2KB)
  const int n4 = (int)(((size_t)16 * PS * 2 + 2048) / 16);
  zero16<<<(n4 + thr - 1) / thr, thr, 0, stream>>>((uint4*)hA, n4);

  void* args[] = {(void*)&x,     (void*)&bih0,  (void*)&bhh0,  (void*)&bih1,  (void*)&bhh1,
                  (void*)&blin,  (void*)&wih0p, (void*)&whh0p, (void*)&wih1p, (void*)&whh1p,
                  (void*)&wlinp, (void*)&hA,    (void*)&hB,    (void*)&out,   (void*)&flags};
  hipLaunchCooperativeKernel((const void*)gru_main, dim3(256), dim3(512), args, 0, stream);
}

// Round 5
// 10034.059 us; speedup vs baseline: 4.6471x; 1.1309x over previous
//
#include <hip/hip_runtime.h>

#define Tn  512
#define Bn  128
#define INn 64
#define Hn  1024

typedef __attribute__((ext_vector_type(8))) short bf16x8;
typedef __attribute__((ext_vector_type(4))) float f32x4;
typedef unsigned short u16;

#define AGENT __HIP_MEMORY_SCOPE_AGENT

__device__ __forceinline__ u16 f2bf(float f) {
  unsigned u = __float_as_uint(f);
  unsigned r = (u + 0x7fffu + ((u >> 16) & 1u)) >> 16;
  return (u16)r;
}
__device__ __forceinline__ float bf2f(u16 h) {
  return __uint_as_float(((unsigned)h) << 16);
}
__device__ __forceinline__ float sigmoidf_(float x) {
  return 1.0f / (1.0f + __expf(-x));
}
__device__ __forceinline__ float tanhf_(float x) {
  float e = __expf(-2.0f * fabsf(x));
  float t = (1.0f - e) / (1.0f + e);
  return copysignf(t, x);
}
__device__ __forceinline__ f32x4 mfma16(bf16x8 a, bf16x8 b, f32x4 c) {
  return __builtin_amdgcn_mfma_f32_16x16x32_bf16(a, b, c, 0, 0, 0);
}
__device__ __forceinline__ size_t hidx(int row, int col) {
  return ((size_t)((row >> 4) * 32 + (col >> 5))) * 512 +
         ((((col >> 3) & 3) * 16 + (row & 15)) * 8) + (col & 7);
}
__device__ __forceinline__ void acq_fence() {
  __builtin_amdgcn_fence(__ATOMIC_ACQUIRE, "agent");
}

__global__ void pack_w(const float* __restrict__ s, u16* __restrict__ d, int R, int K) {
  int tid = blockIdx.x * blockDim.x + threadIdx.x;
  int total = (R * K) >> 3;
  if (tid >= total) return;
  int l = tid & 63;
  int ckc = tid >> 6;
  int nkc = K >> 5;
  int ct = ckc / nkc;
  int kc = ckc - ct * nkc;
  int row = ct * 16 + (l & 15);
  int k0 = kc * 32 + (l >> 4) * 8;
  const float* sp = s + (size_t)row * K + k0;
  float4 a = *(const float4*)sp;
  float4 b = *(const float4*)(sp + 4);
  bf16x8 o;
  u16* op = (u16*)&o;
  op[0] = f2bf(a.x); op[1] = f2bf(a.y); op[2] = f2bf(a.z); op[3] = f2bf(a.w);
  op[4] = f2bf(b.x); op[5] = f2bf(b.y); op[6] = f2bf(b.z); op[7] = f2bf(b.w);
  *(bf16x8*)(d + (size_t)tid * 8) = o;
}

__global__ void zero16(uint4* __restrict__ p, int n4) {
  int i = blockIdx.x * blockDim.x + threadIdx.x;
  if (i < n4) p[i] = make_uint4(0u, 0u, 0u, 0u);
}

#define PS 131072  // one packed [128][1024] plane (elements)
// h ring: [slot(4)][part hi/lo(2)][PS]; step s lives in slot s&3.
// flags: per-block monotone step counters, 128B (32-int) spacing, release-store only.
//   fl0[bg*32+hsl]           at flags + idx*32            (layer0: finished step t -> t+1)
//   fl1[rh*64+cs]            at flags + 4096 + idx*32     (layer1: finished step s -> s+1)
//   flL[bg*4+hsl]            at flags + 8192 + idx*32     (linear: finished step s2 -> s2+1)

__global__ __launch_bounds__(512, 2) void gru_main(
    const float* __restrict__ x,
    const float* __restrict__ b_ih0, const float* __restrict__ b_hh0,
    const float* __restrict__ b_ih1, const float* __restrict__ b_hh1,
    const float* __restrict__ b_lin,
    const u16* __restrict__ wih0p, const u16* __restrict__ whh0p,
    const u16* __restrict__ wih1p, const u16* __restrict__ whh1p,
    const u16* __restrict__ wlinp,
    u16* __restrict__ hA, u16* __restrict__ hB,
    float* __restrict__ out, int* __restrict__ flags) {
  __shared__ float lds[16320];  // layer0: H[2][4][3][16][34]@0 + I[2][3][16][34]@13056
                                // layer1: P[2][8][3][16][20]@0 ; lin: [8][2][16][20]@0

  const int blk  = blockIdx.x;
  const int tid  = threadIdx.x;
  const int w    = tid >> 6;
  const int lane = tid & 63;
  const int ln   = lane & 15;
  const int lq   = lane >> 4;
  const int layer = blk >> 7;
  const int lb   = blk & 127;
  const f32x4 vz = {0.f, 0.f, 0.f, 0.f};

  if (layer == 0) {
    const int bg  = lb >> 5;
    const int hsl = lb & 31;
    const int q   = w & 1;
    const int kg  = w >> 1;
    const int c16 = hsl * 2 + q;
    bf16x8 W[3][8];
#pragma unroll
    for (int g = 0; g < 3; ++g)
#pragma unroll
      for (int kc = 0; kc < 8; ++kc)
        W[g][kc] = *(const bf16x8*)(whh0p + (((size_t)(g * 64 + c16) * 32 + kg * 8 + kc) * 64 + lane) * 8);
    bf16x8 Wx[3][2];
    if (kg == 0) {
#pragma unroll
      for (int g = 0; g < 3; ++g)
#pragma unroll
        for (int kc = 0; kc < 2; ++kc)
          Wx[g][kc] = *(const bf16x8*)(wih0p + (((size_t)(g * 64 + c16) * 2 + kc) * 64 + lane) * 8);
    }
    const bool is_lin = (hsl < 4);
    bf16x8 Wl[4];
    float Blin = 0.f;
    if (is_lin) {
#pragma unroll
      for (int kc = 0; kc < 4; ++kc)
        Wl[kc] = *(const bf16x8*)(wlinp + (((size_t)hsl * 32 + w * 4 + kc) * 64 + lane) * 8);
      Blin = b_lin[hsl * 16 + (tid & 15)];
    }
    const int rm  = tid >> 8;
    const int rr  = (tid >> 4) & 15;
    const int rc2 = (tid & 15) * 2;
    const int ggr = bg * 32 + rm * 16 + rr;
    float Br[2], Bz[2], Bni[2], Bnh[2];
#pragma unroll
    for (int e = 0; e < 2; ++e) {
      const int gc = hsl * 32 + rc2 + e;
      Br[e]  = b_ih0[gc] + b_hh0[gc];
      Bz[e]  = b_ih0[Hn + gc] + b_hh0[Hn + gc];
      Bni[e] = b_ih0[2 * Hn + gc];
      Bnh[e] = b_hh0[2 * Hn + gc];
    }
    // poll pointers (wave 0 only uses them)
    const int* pPeer = flags + ((bg << 5) + (lane & 31)) * 32;            // fl0 own group
    const int* pBp   = flags + 4096 + (((bg >> 1) << 6) + lane) * 32;     // fl1 row-half

    for (int t = 0; t <= Tn + 1; ++t) {
      if (t < Tn) {
        if (w == 0 && t > 0) {   // peers finished t-1 (h0_{t-1} complete)
          while (!__all(__hip_atomic_load(pPeer, __ATOMIC_RELAXED, AGENT) >= t))
            __builtin_amdgcn_s_sleep(1);
          acq_fence();
        }
        __syncthreads();
        const int rs = (t + 3) & 3;
        const int ws_ = t & 3;
        const u16* Ahb = hA + (size_t)(rs * 2 + 0) * PS;
        const u16* Alb = hA + (size_t)(rs * 2 + 1) * PS;
#pragma unroll
        for (int m = 0; m < 2; ++m) {
          const int m16 = bg * 2 + m;
          f32x4 acc[3] = {vz, vz, vz};
          const size_t ab = ((size_t)m16 * 32 + kg * 8) * 512 + lane * 8;
#pragma unroll
          for (int kc = 0; kc < 8; ++kc) {
            bf16x8 ah = *(const bf16x8*)(Ahb + ab + kc * 512);
            bf16x8 al = *(const bf16x8*)(Alb + ab + kc * 512);
            acc[0] = mfma16(ah, W[0][kc], acc[0]);
            acc[1] = mfma16(ah, W[1][kc], acc[1]);
            acc[2] = mfma16(ah, W[2][kc], acc[2]);
            acc[0] = mfma16(al, W[0][kc], acc[0]);
            acc[1] = mfma16(al, W[1][kc], acc[1]);
            acc[2] = mfma16(al, W[2][kc], acc[2]);
          }
          float* Hp = lds + (size_t)(m * 4 + kg) * 1632;
#pragma unroll
          for (int g = 0; g < 3; ++g)
#pragma unroll
            for (int i = 0; i < 4; ++i)
              Hp[g * 544 + (lq * 4 + i) * 34 + q * 16 + ln] = acc[g][i];
          if (kg == 0) {
            f32x4 ax[3] = {vz, vz, vz};
            const float* xr = x + ((size_t)t * Bn + bg * 32 + m * 16 + ln) * INn + lq * 8;
#pragma unroll
            for (int kc = 0; kc < 2; ++kc) {
              float4 v0 = *(const float4*)(xr + kc * 32);
              float4 v1 = *(const float4*)(xr + kc * 32 + 4);
              bf16x8 a;
              u16* ap = (u16*)&a;
              ap[0] = f2bf(v0.x); ap[1] = f2bf(v0.y); ap[2] = f2bf(v0.z); ap[3] = f2bf(v0.w);
              ap[4] = f2bf(v1.x); ap[5] = f2bf(v1.y); ap[6] = f2bf(v1.z); ap[7] = f2bf(v1.w);
              ax[0] = mfma16(a, Wx[0][kc], ax[0]);
              ax[1] = mfma16(a, Wx[1][kc], ax[1]);
              ax[2] = mfma16(a, Wx[2][kc], ax[2]);
            }
            float* Ip = lds + 13056 + (size_t)m * 1632;
#pragma unroll
            for (int g = 0; g < 3; ++g)
#pragma unroll
              for (int i = 0; i < 4; ++i)
                Ip[g * 544 + (lq * 4 + i) * 34 + q * 16 + ln] = ax[g][i];
          }
        }
        __syncthreads();
        if (w == 0 && t >= 4) {  // ring backpressure: layer1 consumed h0_{t-4}
          while (!__all(__hip_atomic_load(pBp, __ATOMIC_RELAXED, AGENT) >= t - 3))
            __builtin_amdgcn_s_sleep(1);
          acq_fence();
        }
        __syncthreads();
        {
          const u16* rhp = Ahb;
          const u16* rlp = Alb;
          u16* whp = hA + (size_t)(ws_ * 2 + 0) * PS;
          u16* wlp = hA + (size_t)(ws_ * 2 + 1) * PS;
#pragma unroll
          for (int e = 0; e < 2; ++e) {
            const int c = rc2 + e;
            const int gc = hsl * 32 + c;
            const float* Ip = lds + 13056 + (size_t)rm * 1632 + rr * 34 + c;
            float I0 = Ip[0], I1 = Ip[544], I2 = Ip[1088];
            float H0 = 0.f, H1 = 0.f, H2 = 0.f;
#pragma unroll
            for (int kgi = 0; kgi < 4; ++kgi) {
              const float* Hp = lds + (size_t)(rm * 4 + kgi) * 1632 + rr * 34 + c;
              H0 += Hp[0]; H1 += Hp[544]; H2 += Hp[1088];
            }
            float r  = sigmoidf_(I0 + H0 + Br[e]);
            float zz = sigmoidf_(I1 + H1 + Bz[e]);
            float nn = tanhf_(I2 + Bni[e] + r * (H2 + Bnh[e]));
            const size_t idx = hidx(ggr, gc);
            float hp = bf2f(rhp[idx]) + bf2f(rlp[idx]);
            float hv = (1.0f - zz) * nn + zz * hp;
            u16 hh = f2bf(hv);
            whp[idx] = hh;
            wlp[idx] = f2bf(hv - bf2f(hh));
          }
        }
        __syncthreads();  // all h0_t stores drained before release
        if (tid == 0)
          __hip_atomic_store(flags + ((bg << 5) + hsl) * 32, t + 1, __ATOMIC_RELEASE, AGENT);
      }
      if (is_lin && t >= 2) {
        const int s2 = t - 2;
        if (w == 0) {  // h2_{t-2} ready: fl1 row-half >= t-1
          while (!__all(__hip_atomic_load(pBp, __ATOMIC_RELAXED, AGENT) >= t - 1))
            __builtin_amdgcn_s_sleep(1);
          acq_fence();
        }
        __syncthreads();
        const int p2 = s2 & 3;
        const u16* Bh = hB + (size_t)(p2 * 2 + 0) * PS;
        const u16* Bl = hB + (size_t)(p2 * 2 + 1) * PS;
        f32x4 la[2] = {vz, vz};
#pragma unroll
        for (int m = 0; m < 2; ++m) {
          const int m16 = bg * 2 + m;
          const size_t ab = ((size_t)m16 * 32 + w * 4) * 512 + lane * 8;
#pragma unroll
          for (int kc = 0; kc < 4; ++kc) {
            bf16x8 ah = *(const bf16x8*)(Bh + ab + kc * 512);
            bf16x8 al = *(const bf16x8*)(Bl + ab + kc * 512);
            la[m] = mfma16(ah, Wl[kc], la[m]);
            la[m] = mfma16(al, Wl[kc], la[m]);
          }
        }
        __syncthreads();
#pragma unroll
        for (int m = 0; m < 2; ++m)
#pragma unroll
          for (int i = 0; i < 4; ++i)
            lds[((w * 2 + m) * 16 + lq * 4 + i) * 20 + ln] = la[m][i];
        __syncthreads();
        {
          const int lm = tid >> 8, lr = (tid >> 4) & 15, lc = tid & 15;
          float s = Blin;
#pragma unroll
          for (int w8 = 0; w8 < 8; ++w8)
            s += lds[((w8 * 2 + lm) * 16 + lr) * 20 + lc];
          out[((size_t)s2 * Bn + bg * 32 + lm * 16 + lr) * 64 + hsl * 16 + lc] = s;
        }
        __syncthreads();
        if (tid == 0)
          __hip_atomic_store(flags + 8192 + ((bg << 2) + hsl) * 32, s2 + 1, __ATOMIC_RELEASE, AGENT);
      }
    }
  } else {
    // ---------------- layer 1 ----------------
    const int cs  = lb >> 1;
    const int rh  = lb & 1;
    const int side = w >> 2;
    const int ks  = w & 3;
    const u16* wsrc = side ? whh1p : wih1p;
    bf16x8 W[3][8];
#pragma unroll
    for (int g = 0; g < 3; ++g)
#pragma unroll
      for (int kc = 0; kc < 8; ++kc)
        W[g][kc] = *(const bf16x8*)(wsrc + (((size_t)(g * 64 + cs) * 32 + ks * 8 + kc) * 64 + lane) * 8);
    const int rm = tid >> 8;
    const int rr = (tid >> 4) & 15;
    const int rc = tid & 15;
    const int ggc = cs * 16 + rc;
    const float Br  = b_ih1[ggc] + b_hh1[ggc];
    const float Bz  = b_ih1[Hn + ggc] + b_hh1[Hn + ggc];
    const float Bni = b_ih1[2 * Hn + ggc];
    const float Bnh = b_hh1[2 * Hn + ggc];
    const int* pA = flags + ((rh << 6) + lane) * 32;                 // fl0: bg=2rh..2rh+1
    const int* pB = flags + 4096 + ((rh << 6) + lane) * 32;          // fl1 own row-half
    const int* pC = flags + 8192 + ((rh << 3) + (lane & 7)) * 32;    // flL row-half

    for (int s = 0; s < Tn; ++s) {
      if (w == 0) {
        for (;;) {
          bool ok = __hip_atomic_load(pA, __ATOMIC_RELAXED, AGENT) >= s + 1;  // h1_s ready
          if (s > 0 && __hip_atomic_load(pB, __ATOMIC_RELAXED, AGENT) < s) ok = false;  // h2_{s-1}
          if (s >= 4 && (lane & 7) == lane &&
              __hip_atomic_load(pC, __ATOMIC_RELAXED, AGENT) < s - 3) ok = false;  // h2 ring
          if (__all(ok)) break;
          __builtin_amdgcn_s_sleep(1);
        }
        acq_fence();
      }
      __syncthreads();
      const int ss = s & 3;
      const int rs = (s + 3) & 3;
      const u16* A1h = hA + (size_t)(ss * 2 + 0) * PS;
      const u16* A1l = hA + (size_t)(ss * 2 + 1) * PS;
      const u16* A2h = hB + (size_t)(rs * 2 + 0) * PS;
      const u16* A2l = hB + (size_t)(rs * 2 + 1) * PS;
      u16* whp = hB + (size_t)(ss * 2 + 0) * PS;
      u16* wlp = hB + (size_t)(ss * 2 + 1) * PS;
      const u16* Ahb = side ? A2h : A1h;
      const u16* Alb = side ? A2l : A1l;
#pragma unroll
      for (int round = 0; round < 2; ++round) {
#pragma unroll
        for (int m = 0; m < 2; ++m) {
          const int m16 = rh * 4 + round * 2 + m;
          f32x4 acc[3] = {vz, vz, vz};
          const size_t ab = ((size_t)m16 * 32 + ks * 8) * 512 + lane * 8;
#pragma unroll
          for (int kc = 0; kc < 8; ++kc) {
            bf16x8 ah = *(const bf16x8*)(Ahb + ab + kc * 512);
            bf16x8 al = *(const bf16x8*)(Alb + ab + kc * 512);
            acc[0] = mfma16(ah, W[0][kc], acc[0]);
            acc[1] = mfma16(ah, W[1][kc], acc[1]);
            acc[2] = mfma16(ah, W[2][kc], acc[2]);
            acc[0] = mfma16(al, W[0][kc], acc[0]);
            acc[1] = mfma16(al, W[1][kc], acc[1]);
            acc[2] = mfma16(al, W[2][kc], acc[2]);
          }
#pragma unroll
          for (int g = 0; g < 3; ++g)
#pragma unroll
            for (int i = 0; i < 4; ++i)
              lds[((m * 8 + w) * 3 + g) * 320 + (lq * 4 + i) * 20 + ln] = acc[g][i];
        }
        __syncthreads();
        {
          float I0 = 0.f, I1 = 0.f, I2 = 0.f, H0 = 0.f, H1 = 0.f, H2 = 0.f;
#pragma unroll
          for (int wi = 0; wi < 4; ++wi) {
            const float* P = lds + ((rm * 8 + wi) * 3) * 320 + rr * 20 + rc;
            I0 += P[0]; I1 += P[320]; I2 += P[640];
          }
#pragma unroll
          for (int wi = 4; wi < 8; ++wi) {
            const float* P = lds + ((rm * 8 + wi) * 3) * 320 + rr * 20 + rc;
            H0 += P[0]; H1 += P[320]; H2 += P[640];
          }
          float r  = sigmoidf_(I0 + H0 + Br);
          float zz = sigmoidf_(I1 + H1 + Bz);
          float nn = tanhf_(I2 + Bni + r * (H2 + Bnh));
          const int gr = rh * 64 + (round * 2 + rm) * 16 + rr;
          const size_t idx = hidx(gr, ggc);
          float hp = bf2f(A2h[idx]) + bf2f(A2l[idx]);
          float hv = (1.0f - zz) * nn + zz * hp;
          u16 hh = f2bf(hv);
          whp[idx] = hh;
          wlp[idx] = f2bf(hv - bf2f(hh));
        }
        __syncthreads();
      }
      if (tid == 0)
        __hip_atomic_store(flags + 4096 + ((rh << 6) + cs) * 32, s + 1, __ATOMIC_RELEASE, AGENT);
    }
  }
}

extern "C" void kernel_launch(void* const* d_in, const int* in_sizes, int n_in,
                              void* d_out, int out_size, void* d_ws, size_t ws_size,
                              hipStream_t stream) {
  (void)in_sizes; (void)n_in; (void)out_size; (void)ws_size;
  const float* x     = (const float*)d_in[0];
  const float* wih0f = (const float*)d_in[1];
  const float* whh0f = (const float*)d_in[2];
  const float* bih0  = (const float*)d_in[3];
  const float* bhh0  = (const float*)d_in[4];
  const float* wih1f = (const float*)d_in[5];
  const float* whh1f = (const float*)d_in[6];
  const float* bih1  = (const float*)d_in[7];
  const float* bhh1  = (const float*)d_in[8];
  const float* wlinf = (const float*)d_in[9];
  const float* blin  = (const float*)d_in[10];
  float* out = (float*)d_out;

  char* w = (char*)d_ws;
  u16* whh0p = (u16*)w; w += (size_t)3072 * 1024 * 2;
  u16* wih1p = (u16*)w; w += (size_t)3072 * 1024 * 2;
  u16* whh1p = (u16*)w; w += (size_t)3072 * 1024 * 2;
  u16* wih0p = (u16*)w; w += (size_t)3072 * 64 * 2;
  u16* wlinp = (u16*)w; w += (size_t)64 * 1024 * 2;
  u16* hA    = (u16*)w; w += (size_t)4 * 2 * PS * 2;  // ring depth 4, hi/lo
  u16* hB    = (u16*)w; w += (size_t)4 * 2 * PS * 2;
  int* flags = (int*)w; w += 36864;                   // 8704 ints used, 128B-spaced

  const int thr = 256;
  pack_w<<<(3072 * 1024 / 8 + thr - 1) / thr, thr, 0, stream>>>(whh0f, whh0p, 3072, 1024);
  pack_w<<<(3072 * 1024 / 8 + thr - 1) / thr, thr, 0, stream>>>(wih1f, wih1p, 3072, 1024);
  pack_w<<<(3072 * 1024 / 8 + thr - 1) / thr, thr, 0, stream>>>(whh1f, whh1p, 3072, 1024);
  pack_w<<<(3072 * 64 / 8 + thr - 1) / thr, thr, 0, stream>>>(wih0f, wih0p, 3072, 64);
  pack_w<<<(64 * 1024 / 8 + thr - 1) / thr, thr, 0, stream>>>(wlinf, wlinp, 64, 1024);
  // zero hA + hB + flags (contiguous: 4MB + 36KB)
  const int n4 = (int)(((size_t)16 * PS * 2 + 36864) / 16);
  zero16<<<(n4 + thr - 1) / thr, thr, 0, stream>>>((uint4*)hA, n4);

  void* args[] = {(void*)&x,     (void*)&bih0,  (void*)&bhh0,  (void*)&bih1,  (void*)&bhh1,
                  (void*)&blin,  (void*)&wih0p, (void*)&whh0p, (void*)&wih1p, (void*)&whh1p,
                  (void*)&wlinp, (void*)&hA,    (void*)&hB,    (void*)&out,   (void*)&flags};
  hipLaunchCooperativeKernel((const void*)gru_main, dim3(256), dim3(512), args, 0, stream);
}

// Round 6
// 9259.443 us; speedup vs baseline: 5.0359x; 1.0837x over previous
//
#include <hip/hip_runtime.h>

#define Tn  512
#define Bn  128
#define INn 64
#define Hn  1024

typedef __attribute__((ext_vector_type(8))) short bf16x8;
typedef __attribute__((ext_vector_type(4))) float f32x4;
typedef unsigned short u16;

#define AGENT __HIP_MEMORY_SCOPE_AGENT

__device__ __forceinline__ u16 f2bf(float f) {
  unsigned u = __float_as_uint(f);
  unsigned r = (u + 0x7fffu + ((u >> 16) & 1u)) >> 16;
  return (u16)r;
}
__device__ __forceinline__ float bf2f(u16 h) {
  return __uint_as_float(((unsigned)h) << 16);
}
__device__ __forceinline__ float sigmoidf_(float x) {
  return 1.0f / (1.0f + __expf(-x));
}
__device__ __forceinline__ float tanhf_(float x) {
  float e = __expf(-2.0f * fabsf(x));
  float t = (1.0f - e) / (1.0f + e);
  return copysignf(t, x);
}
__device__ __forceinline__ f32x4 mfma16(bf16x8 a, bf16x8 b, f32x4 c) {
  return __builtin_amdgcn_mfma_f32_16x16x32_bf16(a, b, c, 0, 0, 0);
}
__device__ __forceinline__ size_t hidx(int row, int col) {
  return ((size_t)((row >> 4) * 32 + (col >> 5))) * 512 +
         ((((col >> 3) & 3) * 16 + (row & 15)) * 8) + (col & 7);
}
__device__ __forceinline__ void acq_fence() {
  __builtin_amdgcn_fence(__ATOMIC_ACQUIRE, "agent");
}
// batch-load 8 fragments (4 kc x hi/lo) -> all in flight before first use
__device__ __forceinline__ void ldb8(bf16x8 dst[8], const u16* __restrict__ h,
                                     const u16* __restrict__ l, size_t ab, int kc0) {
#pragma unroll
  for (int k = 0; k < 4; ++k) {
    dst[2 * k]     = *(const bf16x8*)(h + ab + (size_t)(kc0 + k) * 512);
    dst[2 * k + 1] = *(const bf16x8*)(l + ab + (size_t)(kc0 + k) * 512);
  }
}
__device__ __forceinline__ void fma24(f32x4 acc[3], const bf16x8 b[8],
                                      const bf16x8 W[3][8], int kc0) {
#pragma unroll
  for (int k = 0; k < 4; ++k) {
#pragma unroll
    for (int g = 0; g < 3; ++g) {
      acc[g] = mfma16(b[2 * k], W[g][kc0 + k], acc[g]);
      acc[g] = mfma16(b[2 * k + 1], W[g][kc0 + k], acc[g]);
    }
  }
}

__global__ void pack_w(const float* __restrict__ s, u16* __restrict__ d, int R, int K) {
  int tid = blockIdx.x * blockDim.x + threadIdx.x;
  int total = (R * K) >> 3;
  if (tid >= total) return;
  int l = tid & 63;
  int ckc = tid >> 6;
  int nkc = K >> 5;
  int ct = ckc / nkc;
  int kc = ckc - ct * nkc;
  int row = ct * 16 + (l & 15);
  int k0 = kc * 32 + (l >> 4) * 8;
  const float* sp = s + (size_t)row * K + k0;
  float4 a = *(const float4*)sp;
  float4 b = *(const float4*)(sp + 4);
  bf16x8 o;
  u16* op = (u16*)&o;
  op[0] = f2bf(a.x); op[1] = f2bf(a.y); op[2] = f2bf(a.z); op[3] = f2bf(a.w);
  op[4] = f2bf(b.x); op[5] = f2bf(b.y); op[6] = f2bf(b.z); op[7] = f2bf(b.w);
  *(bf16x8*)(d + (size_t)tid * 8) = o;
}

__global__ void zero16(uint4* __restrict__ p, int n4) {
  int i = blockIdx.x * blockDim.x + threadIdx.x;
  if (i < n4) p[i] = make_uint4(0u, 0u, 0u, 0u);
}

#define PS 131072  // one packed [128][1024] plane (elements)
// h ring: [slot(4)][part hi/lo(2)][PS]; step s lives in slot s&3.
// flags: per-block monotone counters, 128B spacing, release-store only.

__global__ __launch_bounds__(512, 2) void gru_main(
    const float* __restrict__ x,
    const float* __restrict__ b_ih0, const float* __restrict__ b_hh0,
    const float* __restrict__ b_ih1, const float* __restrict__ b_hh1,
    const float* __restrict__ b_lin,
    const u16* __restrict__ wih0p, const u16* __restrict__ whh0p,
    const u16* __restrict__ wih1p, const u16* __restrict__ whh1p,
    const u16* __restrict__ wlinp,
    u16* __restrict__ hA, u16* __restrict__ hB,
    float* __restrict__ out, int* __restrict__ flags) {
  __shared__ float lds[16320];  // layer0: H[2m][4kg][3][16][34]@0 + I[2m][3][16][34]@13056
                                // layer1: P[2m][8w][3][16][20]@0 ; lin: [8][2][16][20]@0

  const int blk  = blockIdx.x;
  const int tid  = threadIdx.x;
  const int w    = tid >> 6;
  const int lane = tid & 63;
  const int ln   = lane & 15;
  const int lq   = lane >> 4;
  const int layer = blk >> 7;
  const int lb   = blk & 127;
  const f32x4 vz = {0.f, 0.f, 0.f, 0.f};

  if (layer == 0) {
    const int bg  = lb >> 5;
    const int hsl = lb & 31;
    const int q   = w & 1;
    const int kg  = w >> 1;
    const int c16 = hsl * 2 + q;
    const bool kgl = (kg < 2);
    const int xm  = kg;  // x-gemm m-tile for kg<2 waves
    bf16x8 W[3][8];
#pragma unroll
    for (int g = 0; g < 3; ++g)
#pragma unroll
      for (int kc = 0; kc < 8; ++kc)
        W[g][kc] = *(const bf16x8*)(whh0p + (((size_t)(g * 64 + c16) * 32 + kg * 8 + kc) * 64 + lane) * 8);
    bf16x8 Wx[3][2];
    if (kgl) {
#pragma unroll
      for (int g = 0; g < 3; ++g)
#pragma unroll
        for (int kc = 0; kc < 2; ++kc)
          Wx[g][kc] = *(const bf16x8*)(wih0p + (((size_t)(g * 64 + c16) * 2 + kc) * 64 + lane) * 8);
    }
    const bool is_lin = (hsl < 4);
    float Blin = 0.f;
    if (is_lin) Blin = b_lin[hsl * 16 + (tid & 15)];
    const int rm  = tid >> 8;
    const int rr  = (tid >> 4) & 15;
    const int rc2 = (tid & 15) * 2;
    const int ggr = bg * 32 + rm * 16 + rr;
    float Br[2], Bz[2], Bni[2], Bnh[2];
#pragma unroll
    for (int e = 0; e < 2; ++e) {
      const int gc = hsl * 32 + rc2 + e;
      Br[e]  = b_ih0[gc] + b_hh0[gc];
      Bz[e]  = b_ih0[Hn + gc] + b_hh0[Hn + gc];
      Bni[e] = b_ih0[2 * Hn + gc];
      Bnh[e] = b_hh0[2 * Hn + gc];
    }
    const int* pPeer = flags + ((bg << 5) + (lane & 31)) * 32;
    const int* pBp   = flags + 4096 + (((bg >> 1) << 6) + lane) * 32;

    for (int t = 0; t <= Tn + 1; ++t) {
      if (t < Tn) {
        if (w == 0) {  // merged poll: peers done t-1, layer1 consumed h0_{t-4}
          for (;;) {
            bool ok = true;
            if (t > 0 && __hip_atomic_load(pPeer, __ATOMIC_RELAXED, AGENT) < t) ok = false;
            if (t >= 4 && __hip_atomic_load(pBp, __ATOMIC_RELAXED, AGENT) < t - 3) ok = false;
            if (!__all(ok)) { __builtin_amdgcn_s_sleep(1); continue; }
            break;
          }
          acq_fence();
        }
        __syncthreads();
        const int rs = (t + 3) & 3;
        const int ws_ = t & 3;
        const u16* Ahb = hA + (size_t)(rs * 2 + 0) * PS;
        const u16* Alb = hA + (size_t)(rs * 2 + 1) * PS;
        float4 xv0, xv1, xv2, xv3;
        if (kgl) {  // x loads first: long latency hidden behind h-gemm
          const float* xr = x + ((size_t)t * Bn + bg * 32 + xm * 16 + ln) * INn + lq * 8;
          xv0 = *(const float4*)xr;        xv1 = *(const float4*)(xr + 4);
          xv2 = *(const float4*)(xr + 32); xv3 = *(const float4*)(xr + 36);
        }
        f32x4 acc0[3] = {vz, vz, vz}, acc1[3] = {vz, vz, vz};
        bf16x8 buf[8];
        const size_t ab0 = ((size_t)(bg * 2 + 0) * 32 + kg * 8) * 512 + lane * 8;
        const size_t ab1 = ((size_t)(bg * 2 + 1) * 32 + kg * 8) * 512 + lane * 8;
        ldb8(buf, Ahb, Alb, ab0, 0); fma24(acc0, buf, W, 0);
        ldb8(buf, Ahb, Alb, ab0, 4); fma24(acc0, buf, W, 4);
        ldb8(buf, Ahb, Alb, ab1, 0); fma24(acc1, buf, W, 0);
        ldb8(buf, Ahb, Alb, ab1, 4); fma24(acc1, buf, W, 4);
        {
          float* Hp0 = lds + (size_t)(0 * 4 + kg) * 1632;
          float* Hp1 = lds + (size_t)(1 * 4 + kg) * 1632;
#pragma unroll
          for (int g = 0; g < 3; ++g)
#pragma unroll
            for (int i = 0; i < 4; ++i) {
              Hp0[g * 544 + (lq * 4 + i) * 34 + q * 16 + ln] = acc0[g][i];
              Hp1[g * 544 + (lq * 4 + i) * 34 + q * 16 + ln] = acc1[g][i];
            }
        }
        if (kgl) {
          bf16x8 a0, a1;
          u16* a0p = (u16*)&a0;
          u16* a1p = (u16*)&a1;
          a0p[0] = f2bf(xv0.x); a0p[1] = f2bf(xv0.y); a0p[2] = f2bf(xv0.z); a0p[3] = f2bf(xv0.w);
          a0p[4] = f2bf(xv1.x); a0p[5] = f2bf(xv1.y); a0p[6] = f2bf(xv1.z); a0p[7] = f2bf(xv1.w);
          a1p[0] = f2bf(xv2.x); a1p[1] = f2bf(xv2.y); a1p[2] = f2bf(xv2.z); a1p[3] = f2bf(xv2.w);
          a1p[4] = f2bf(xv3.x); a1p[5] = f2bf(xv3.y); a1p[6] = f2bf(xv3.z); a1p[7] = f2bf(xv3.w);
          f32x4 ax[3] = {vz, vz, vz};
#pragma unroll
          for (int g = 0; g < 3; ++g) {
            ax[g] = mfma16(a0, Wx[g][0], ax[g]);
            ax[g] = mfma16(a1, Wx[g][1], ax[g]);
          }
          float* Ip = lds + 13056 + (size_t)xm * 1632;
#pragma unroll
          for (int g = 0; g < 3; ++g)
#pragma unroll
            for (int i = 0; i < 4; ++i)
              Ip[g * 544 + (lq * 4 + i) * 34 + q * 16 + ln] = ax[g][i];
        }
        __syncthreads();
        {
          const u16* rhp = Ahb;
          const u16* rlp = Alb;
          u16* whp = hA + (size_t)(ws_ * 2 + 0) * PS;
          u16* wlp = hA + (size_t)(ws_ * 2 + 1) * PS;
#pragma unroll
          for (int e = 0; e < 2; ++e) {
            const int c = rc2 + e;
            const int gc = hsl * 32 + c;
            const float* Ip = lds + 13056 + (size_t)rm * 1632 + rr * 34 + c;
            float I0 = Ip[0], I1 = Ip[544], I2 = Ip[1088];
            float H0 = 0.f, H1 = 0.f, H2 = 0.f;
#pragma unroll
            for (int kgi = 0; kgi < 4; ++kgi) {
              const float* Hp = lds + (size_t)(rm * 4 + kgi) * 1632 + rr * 34 + c;
              H0 += Hp[0]; H1 += Hp[544]; H2 += Hp[1088];
            }
            float r  = sigmoidf_(I0 + H0 + Br[e]);
            float zz = sigmoidf_(I1 + H1 + Bz[e]);
            float nn = tanhf_(I2 + Bni[e] + r * (H2 + Bnh[e]));
            const size_t idx = hidx(ggr, gc);
            float hp = bf2f(rhp[idx]) + bf2f(rlp[idx]);
            float hv = (1.0f - zz) * nn + zz * hp;
            u16 hh = f2bf(hv);
            whp[idx] = hh;
            wlp[idx] = f2bf(hv - bf2f(hh));
          }
        }
        __syncthreads();  // all h0_t stores drained before release
        if (tid == 0)
          __hip_atomic_store(flags + ((bg << 5) + hsl) * 32, t + 1, __ATOMIC_RELEASE, AGENT);
      }
      if (is_lin && t >= 2) {
        const int s2 = t - 2;
        if (w == 0) {  // h2_{t-2} ready: fl1 row-half >= t-1
          while (!__all(__hip_atomic_load(pBp, __ATOMIC_RELAXED, AGENT) >= t - 1))
            __builtin_amdgcn_s_sleep(1);
          acq_fence();
        }
        __syncthreads();
        const int p2 = s2 & 3;
        const u16* Bh = hB + (size_t)(p2 * 2 + 0) * PS;
        const u16* Bl = hB + (size_t)(p2 * 2 + 1) * PS;
        bf16x8 Wl[4];
#pragma unroll
        for (int kc = 0; kc < 4; ++kc)
          Wl[kc] = *(const bf16x8*)(wlinp + (((size_t)hsl * 32 + w * 4 + kc) * 64 + lane) * 8);
        f32x4 la0 = vz, la1 = vz;
        bf16x8 buf2[8];
        const size_t abL0 = ((size_t)(bg * 2 + 0) * 32 + w * 4) * 512 + lane * 8;
        const size_t abL1 = ((size_t)(bg * 2 + 1) * 32 + w * 4) * 512 + lane * 8;
        ldb8(buf2, Bh, Bl, abL0, 0);
#pragma unroll
        for (int k = 0; k < 4; ++k) {
          la0 = mfma16(buf2[2 * k], Wl[k], la0);
          la0 = mfma16(buf2[2 * k + 1], Wl[k], la0);
        }
        ldb8(buf2, Bh, Bl, abL1, 0);
#pragma unroll
        for (int k = 0; k < 4; ++k) {
          la1 = mfma16(buf2[2 * k], Wl[k], la1);
          la1 = mfma16(buf2[2 * k + 1], Wl[k], la1);
        }
        __syncthreads();  // GRU-phase LDS reads complete
#pragma unroll
        for (int i = 0; i < 4; ++i) {
          lds[((w * 2 + 0) * 16 + lq * 4 + i) * 20 + ln] = la0[i];
          lds[((w * 2 + 1) * 16 + lq * 4 + i) * 20 + ln] = la1[i];
        }
        __syncthreads();
        {
          const int lm = tid >> 8, lr = (tid >> 4) & 15, lc = tid & 15;
          float s = Blin;
#pragma unroll
          for (int w8 = 0; w8 < 8; ++w8)
            s += lds[((w8 * 2 + lm) * 16 + lr) * 20 + lc];
          out[((size_t)s2 * Bn + bg * 32 + lm * 16 + lr) * 64 + hsl * 16 + lc] = s;
        }
        __syncthreads();
        if (tid == 0)
          __hip_atomic_store(flags + 8192 + ((bg << 2) + hsl) * 32, s2 + 1, __ATOMIC_RELEASE, AGENT);
      }
    }
  } else {
    // ---------------- layer 1 ----------------
    const int cs  = lb >> 1;
    const int rh  = lb & 1;
    const int side = w >> 2;
    const int ks  = w & 3;
    const u16* wsrc = side ? whh1p : wih1p;
    bf16x8 W[3][8];
#pragma unroll
    for (int g = 0; g < 3; ++g)
#pragma unroll
      for (int kc = 0; kc < 8; ++kc)
        W[g][kc] = *(const bf16x8*)(wsrc + (((size_t)(g * 64 + cs) * 32 + ks * 8 + kc) * 64 + lane) * 8);
    const int rm = tid >> 8;
    const int rr = (tid >> 4) & 15;
    const int rc = tid & 15;
    const int ggc = cs * 16 + rc;
    const float Br  = b_ih1[ggc] + b_hh1[ggc];
    const float Bz  = b_ih1[Hn + ggc] + b_hh1[Hn + ggc];
    const float Bni = b_ih1[2 * Hn + ggc];
    const float Bnh = b_hh1[2 * Hn + ggc];
    const int* pA = flags + ((rh << 6) + lane) * 32;
    const int* pB = flags + 4096 + ((rh << 6) + lane) * 32;
    const int* pC = flags + 8192 + ((rh << 3) + (lane & 7)) * 32;

    for (int s = 0; s < Tn; ++s) {
      if (w == 0) {
        for (;;) {
          bool ok = __hip_atomic_load(pA, __ATOMIC_RELAXED, AGENT) >= s + 1;
          if (s > 0 && __hip_atomic_load(pB, __ATOMIC_RELAXED, AGENT) < s) ok = false;
          if (s >= 4 && (lane & 7) == lane &&
              __hip_atomic_load(pC, __ATOMIC_RELAXED, AGENT) < s - 3) ok = false;
          if (__all(ok)) break;
          __builtin_amdgcn_s_sleep(1);
        }
        acq_fence();
      }
      __syncthreads();
      const int ss = s & 3;
      const int rs = (s + 3) & 3;
      const u16* A1h = hA + (size_t)(ss * 2 + 0) * PS;
      const u16* A1l = hA + (size_t)(ss * 2 + 1) * PS;
      const u16* A2h = hB + (size_t)(rs * 2 + 0) * PS;
      const u16* A2l = hB + (size_t)(rs * 2 + 1) * PS;
      u16* whp = hB + (size_t)(ss * 2 + 0) * PS;
      u16* wlp = hB + (size_t)(ss * 2 + 1) * PS;
      const u16* Ahb = side ? A2h : A1h;
      const u16* Alb = side ? A2l : A1l;
#pragma unroll
      for (int round = 0; round < 2; ++round) {
        const int mA = rh * 4 + round * 2;
        f32x4 acc0[3] = {vz, vz, vz}, acc1[3] = {vz, vz, vz};
        bf16x8 bA[8], bB[8];
        const size_t abR0 = ((size_t)mA * 32 + ks * 8) * 512 + lane * 8;
        const size_t abR1 = ((size_t)(mA + 1) * 32 + ks * 8) * 512 + lane * 8;
        // software-pipelined: two buffers, next batch issued before prior consumed
        ldb8(bA, Ahb, Alb, abR0, 0);
        ldb8(bB, Ahb, Alb, abR0, 4);
        fma24(acc0, bA, W, 0);
        ldb8(bA, Ahb, Alb, abR1, 0);
        fma24(acc0, bB, W, 4);
#pragma unroll
        for (int g = 0; g < 3; ++g)
#pragma unroll
          for (int i = 0; i < 4; ++i)
            lds[((0 * 8 + w) * 3 + g) * 320 + (lq * 4 + i) * 20 + ln] = acc0[g][i];
        ldb8(bB, Ahb, Alb, abR1, 4);
        fma24(acc1, bA, W, 0);
        fma24(acc1, bB, W, 4);
#pragma unroll
        for (int g = 0; g < 3; ++g)
#pragma unroll
          for (int i = 0; i < 4; ++i)
            lds[((1 * 8 + w) * 3 + g) * 320 + (lq * 4 + i) * 20 + ln] = acc1[g][i];
        __syncthreads();
        {
          float I0 = 0.f, I1 = 0.f, I2 = 0.f, H0 = 0.f, H1 = 0.f, H2 = 0.f;
#pragma unroll
          for (int wi = 0; wi < 4; ++wi) {
            const float* P = lds + ((rm * 8 + wi) * 3) * 320 + rr * 20 + rc;
            I0 += P[0]; I1 += P[320]; I2 += P[640];
          }
#pragma unroll
          for (int wi = 4; wi < 8; ++wi) {
            const float* P = lds + ((rm * 8 + wi) * 3) * 320 + rr * 20 + rc;
            H0 += P[0]; H1 += P[320]; H2 += P[640];
          }
          float r  = sigmoidf_(I0 + H0 + Br);
          float zz = sigmoidf_(I1 + H1 + Bz);
          float nn = tanhf_(I2 + Bni + r * (H2 + Bnh));
          const int gr = rh * 64 + (round * 2 + rm) * 16 + rr;
          const size_t idx = hidx(gr, ggc);
          float hp = bf2f(A2h[idx]) + bf2f(A2l[idx]);
          float hv = (1.0f - zz) * nn + zz * hp;
          u16 hh = f2bf(hv);
          whp[idx] = hh;
          wlp[idx] = f2bf(hv - bf2f(hh));
        }
        __syncthreads();
      }
      if (tid == 0)
        __hip_atomic_store(flags + 4096 + ((rh << 6) + cs) * 32, s + 1, __ATOMIC_RELEASE, AGENT);
    }
  }
}

extern "C" void kernel_launch(void* const* d_in, const int* in_sizes, int n_in,
                              void* d_out, int out_size, void* d_ws, size_t ws_size,
                              hipStream_t stream) {
  (void)in_sizes; (void)n_in; (void)out_size; (void)ws_size;
  const float* x     = (const float*)d_in[0];
  const float* wih0f = (const float*)d_in[1];
  const float* whh0f = (const float*)d_in[2];
  const float* bih0  = (const float*)d_in[3];
  const float* bhh0  = (const float*)d_in[4];
  const float* wih1f = (const float*)d_in[5];
  const float* whh1f = (const float*)d_in[6];
  const float* bih1  = (const float*)d_in[7];
  const float* bhh1  = (const float*)d_in[8];
  const float* wlinf = (const float*)d_in[9];
  const float* blin  = (const float*)d_in[10];
  float* out = (float*)d_out;

  char* w = (char*)d_ws;
  u16* whh0p = (u16*)w; w += (size_t)3072 * 1024 * 2;
  u16* wih1p = (u16*)w; w += (size_t)3072 * 1024 * 2;
  u16* whh1p = (u16*)w; w += (size_t)3072 * 1024 * 2;
  u16* wih0p = (u16*)w; w += (size_t)3072 * 64 * 2;
  u16* wlinp = (u16*)w; w += (size_t)64 * 1024 * 2;
  u16* hA    = (u16*)w; w += (size_t)4 * 2 * PS * 2;  // ring depth 4, hi/lo
  u16* hB    = (u16*)w; w += (size_t)4 * 2 * PS * 2;
  int* flags = (int*)w; w += 36864;

  const int thr = 256;
  pack_w<<<(3072 * 1024 / 8 + thr - 1) / thr, thr, 0, stream>>>(whh0f, whh0p, 3072, 1024);
  pack_w<<<(3072 * 1024 / 8 + thr - 1) / thr, thr, 0, stream>>>(wih1f, wih1p, 3072, 1024);
  pack_w<<<(3072 * 1024 / 8 + thr - 1) / thr, thr, 0, stream>>>(whh1f, whh1p, 3072, 1024);
  pack_w<<<(3072 * 64 / 8 + thr - 1) / thr, thr, 0, stream>>>(wih0f, wih0p, 3072, 64);
  pack_w<<<(64 * 1024 / 8 + thr - 1) / thr, thr, 0, stream>>>(wlinf, wlinp, 64, 1024);
  const int n4 = (int)(((size_t)16 * PS * 2 + 36864) / 16);
  zero16<<<(n4 + thr - 1) / thr, thr, 0, stream>>>((uint4*)hA, n4);

  void* args[] = {(void*)&x,     (void*)&bih0,  (void*)&bhh0,  (void*)&bih1,  (void*)&bhh1,
                  (void*)&blin,  (void*)&wih0p, (void*)&whh0p, (void*)&wih1p, (void*)&whh1p,
                  (void*)&wlinp, (void*)&hA,    (void*)&hB,    (void*)&out,   (void*)&flags};
  hipLaunchCooperativeKernel((const void*)gru_main, dim3(256), dim3(512), args, 0, stream);
}